// Round 8
// baseline (717.585 us; speedup 1.0000x reference)
//
#include <hip/hip_runtime.h>
#include <hip/hip_bf16.h>
#include <math.h>

#define HD 128
#define NPB 512        // nodes per bucket
#define CAP 16384      // edge capacity per bucket (avg ~8163 -> 2x headroom)
#define SCHUNK 4096    // edges per scatter block
#define FTILE 32       // nodes per fused-layer block
#define ALCSR 1536     // staged csr entries per 32-node block (avg ~522)

typedef __attribute__((ext_vector_type(8))) short  bf16x8;
typedef __attribute__((ext_vector_type(4))) float  f32x4;

__device__ __forceinline__ float lrelu(float v) { return v > 0.0f ? v : 0.1f * v; }

__device__ __forceinline__ unsigned short f2bf(float f) {
  union { float f; unsigned u; } c; c.f = f;
  unsigned u = c.u + 0x7fffu + ((c.u >> 16) & 1u);   // RNE
  return (unsigned short)(u >> 16);
}
__device__ __forceinline__ float bf2f(unsigned short u) {
  return __uint_as_float((unsigned)u << 16);
}

// ---------------- embedding layer 1 (all types, padded node ids) ----------------
__global__ __launch_bounds__(256)
void embed1_kernel(const float* __restrict__ xg, const float* __restrict__ xl,
                   const float* __restrict__ xo, const float* __restrict__ xe,
                   const float* __restrict__ Wg, const float* __restrict__ bg,
                   const float* __restrict__ Wl, const float* __restrict__ bl,
                   const float* __restrict__ Wo, const float* __restrict__ bo,
                   const float* __restrict__ We, const float* __restrict__ be,
                   unsigned short* __restrict__ h1, int4 padCum, int4 realCnt) {
  int p = blockIdx.x * 2 + (threadIdx.x >> 7);
  if (p >= padCum.w) return;
  int j = threadIdx.x & 127;
  int typ = (p < padCum.x) ? 0 : (p < padCum.y) ? 1 : (p < padCum.z) ? 2 : 3;
  int padStart = (typ == 0) ? 0 : (typ == 1) ? padCum.x : (typ == 2) ? padCum.y : padCum.z;
  int cnt = (typ == 0) ? realCnt.x : (typ == 1) ? realCnt.y : (typ == 2) ? realCnt.z : realCnt.w;
  int loc = p - padStart;
  if (loc >= cnt) return;
  const float *x, *W, *bb; int IN;
  if (typ == 0)      { x = xg; W = Wg; bb = bg; IN = 3; }
  else if (typ == 1) { x = xl; W = Wl; bb = bl; IN = 3; }
  else if (typ == 2) { x = xo; W = Wo; bb = bo; IN = 6; }
  else               { x = xe; W = We; bb = be; IN = 6; }
  float acc = bb[j];
  for (int k = 0; k < IN; k++) acc += x[(size_t)loc * IN + k] * W[k * HD + j];
  h1[(size_t)p * HD + j] = f2bf(lrelu(acc));
}

// ---------------- weight repack + invptv + gcnt zero ----------------
__global__ __launch_bounds__(256)
void wprep_all_kernel(const float* __restrict__ Wg2, const float* __restrict__ Wld2,
                      const float* __restrict__ Wor2, const float* __restrict__ Wex2,
                      const float* __restrict__ Wl_h, const float* __restrict__ Wr_h,
                      unsigned short* __restrict__ Wp,
                      const int* __restrict__ ptv, int* __restrict__ inv,
                      int* __restrict__ gcnt, int n) {
  int tid = blockIdx.x * 256 + threadIdx.x;      // 10 * 16384 total
  if (tid < 256) gcnt[tid] = 0;
  if (tid < n) inv[ptv[tid]] = tid;
  int m = tid >> 14;
  int i = tid & 16383;
  const float* src; unsigned short* dst;
  switch (m) {
    case 0: src = Wg2;  dst = Wp;             break;
    case 1: src = Wld2; dst = Wp + 16384;     break;
    case 2: src = Wor2; dst = Wp + 2 * 16384; break;
    case 3: src = Wex2; dst = Wp + 3 * 16384; break;
    default: {
      int mm = m - 4; int l = mm >> 1; int isR = mm & 1;
      src = (isR ? Wr_h : Wl_h) + (size_t)l * 16384;
      dst = Wp + 4 * 16384 + (size_t)l * 32768 + (isR ? 16384 : 0);
    }
  }
  int k = i >> 7, j = i & 127;
  int ks = k >> 5, g = (k >> 3) & 3, b = k & 7;
  dst[((ks * 128 + j) * 4 + g) * 8 + b] = f2bf(src[i]);
}

// ---------------- embedding layer 2 (MFMA), row-major out via invp ----------------
__global__ __launch_bounds__(256)
void mfma_embed2_kernel(const unsigned short* __restrict__ h1,
                        const unsigned short* __restrict__ Wp,
                        const float* __restrict__ b_g, const float* __restrict__ b_ld,
                        const float* __restrict__ b_or, const float* __restrict__ b_ex,
                        const int* __restrict__ inv, unsigned short* __restrict__ out,
                        int4 padCum, int4 realStart, int4 realCnt) {
  const int t = threadIdx.x, w = t >> 6, l = t & 63;
  const int lr = l & 15, lg = l >> 4;
  const int prow0 = blockIdx.x * 64 + w * 16;
  int typ = (prow0 < padCum.x) ? 0 : (prow0 < padCum.y) ? 1 : (prow0 < padCum.z) ? 2 : 3;
  int padStart = (typ == 0) ? 0 : (typ == 1) ? padCum.x : (typ == 2) ? padCum.y : padCum.z;
  int rStart = (typ == 0) ? realStart.x : (typ == 1) ? realStart.y : (typ == 2) ? realStart.z : realStart.w;
  int cnt = (typ == 0) ? realCnt.x : (typ == 1) ? realCnt.y : (typ == 2) ? realCnt.z : realCnt.w;
  const float* bias = (typ == 0) ? b_g : (typ == 1) ? b_ld : (typ == 2) ? b_or : b_ex;

  int raLoc = prow0 + lr - padStart; if (raLoc >= cnt) raLoc = cnt - 1;
  const unsigned short* abase = h1 + (size_t)(padStart + raLoc) * HD + 8 * lg;
  const unsigned short* wbase = Wp + (size_t)typ * 16384 + lr * 32 + lg * 8;

  f32x4 acc[8];
  #pragma unroll
  for (int cb = 0; cb < 8; cb++) {
    float bv = bias[cb * 16 + lr];
    acc[cb] = (f32x4){bv, bv, bv, bv};
  }
  #pragma unroll
  for (int ks = 0; ks < 4; ks++) {
    bf16x8 af = *(const bf16x8*)(abase + ks * 32);
    #pragma unroll
    for (int cb = 0; cb < 8; cb++) {
      bf16x8 bfv = *(const bf16x8*)(wbase + (size_t)(ks * 128 + cb * 16) * 32);
      acc[cb] = __builtin_amdgcn_mfma_f32_16x16x32_bf16(af, bfv, acc[cb], 0, 0, 0);
    }
  }
  int tgt[4];
  #pragma unroll
  for (int r = 0; r < 4; r++) {
    int locRow = prow0 + lg * 4 + r - padStart;
    tgt[r] = (locRow < cnt) ? inv[rStart + locRow] : -1;
  }
  #pragma unroll
  for (int cb = 0; cb < 8; cb++) {
    #pragma unroll
    for (int r = 0; r < 4; r++) {
      if (tgt[r] >= 0)
        out[(size_t)tgt[r] * HD + cb * 16 + lr] = f2bf(lrelu(acc[cb][r]));
    }
  }
}

// ---------------- CSR build phase 1: bucket scatter (packed int) ----------------
__global__ __launch_bounds__(256)
void bucket_scatter_kernel(const int* __restrict__ esrc, const int* __restrict__ edst,
                           int* __restrict__ gcnt, int* __restrict__ ebuf, int nE) {
  __shared__ int cnt[256];
  __shared__ int cur[256];
  const int t = threadIdx.x;
  const int c0 = blockIdx.x * SCHUNK;
  int s_arr[16], d_arr[16];
  cnt[t] = 0;
  __syncthreads();
  #pragma unroll
  for (int k = 0; k < 16; k++) {
    int idx = c0 + k * 256 + t;
    if (idx < nE) {
      s_arr[k] = esrc[idx];
      int d = edst[idx];
      d_arr[k] = d;
      atomicAdd(&cnt[d >> 9], 1);
    } else d_arr[k] = -1;
  }
  __syncthreads();
  if (cnt[t] > 0) cur[t] = atomicAdd(&gcnt[t], cnt[t]);
  __syncthreads();
  #pragma unroll
  for (int k = 0; k < 16; k++) {
    if (d_arr[k] >= 0) {
      int b = d_arr[k] >> 9;
      int p = atomicAdd(&cur[b], 1);
      ebuf[(size_t)b * CAP + p] = (s_arr[k] << 9) | (d_arr[k] & 511);
    }
  }
}

__device__ __forceinline__ int wave_incl_scan(int v) {
  int lane = threadIdx.x & 63;
  #pragma unroll
  for (int d = 1; d < 64; d <<= 1) {
    int tv = __shfl_up(v, d, 64);
    if (lane >= d) v += tv;
  }
  return v;
}

// ---------------- CSR build phase 2: per-bucket local build ----------------
__global__ __launch_bounds__(256)
void bucket_build_kernel(const int* __restrict__ ebuf, const int* __restrict__ gcnt,
                         int* __restrict__ csr, int* __restrict__ offs,
                         int* __restrict__ deg, float* __restrict__ inv_deg, int n) {
  __shared__ int hist[512];
  __shared__ int offl[512];
  __shared__ int wsum[4];
  const int b = blockIdx.x, t = threadIdx.x;
  const int cnt = gcnt[b];
  const size_t ebase = (size_t)b * CAP;
  hist[t] = 0; hist[t + 256] = 0;
  __syncthreads();
  for (int i = t; i < cnt; i += 256) {
    int e = ebuf[ebase + i];
    atomicAdd(&hist[e & 511], 1);
  }
  __syncthreads();
  int a0 = hist[2 * t], a1 = hist[2 * t + 1];
  int s = a0 + a1;
  int incl = wave_incl_scan(s);
  int wid = t >> 6;
  if ((t & 63) == 63) wsum[wid] = incl;
  __syncthreads();
  int wbase = 0;
  for (int w_ = 0; w_ < wid; w_++) wbase += wsum[w_];
  int excl = wbase + incl - s;
  offl[2 * t] = excl;
  offl[2 * t + 1] = excl + a0;
  __syncthreads();
  const int d0 = b << 9;
  for (int i = t; i < 512; i += 256) {
    int g = d0 + i;
    if (g < n) {
      offs[g] = b * CAP + offl[i];
      int dg = hist[i];
      deg[g] = dg;
      inv_deg[g] = 1.0f / fmaxf((float)dg, 1.0f);
    }
  }
  __syncthreads();
  for (int i = t; i < cnt; i += 256) {
    int e = ebuf[ebase + i];
    int p = atomicAdd(&offl[e & 511], 1);
    csr[ebase + p] = ((unsigned)e) >> 9;
  }
}

// ---------------- fused SAGE layer: gather-mean + MFMA combine (32-node tile) ----------------
// Gather: wave = 4 nodes x 16 lanes x 16B (4 full 64B lines/edge), 2 passes,
// 4-chain edge ILP. Mean rows -> LDS (stride 136). MFMA: 2 row-tiles; wave w
// owns col-frags 2w,2w+1 for BOTH tiles (weight frag loaded once, used twice).
template<bool EMIT_Z>
__global__ __launch_bounds__(256)
void sage_fused_kernel(const unsigned short* __restrict__ x, const int* __restrict__ csr,
                       const int* __restrict__ offs, const int* __restrict__ deg,
                       const float* __restrict__ inv_deg,
                       const unsigned short* __restrict__ Wp, const float* __restrict__ bias,
                       unsigned short* __restrict__ out,
                       const float* __restrict__ wl, const float* __restrict__ wr,
                       float* __restrict__ zl, float* __restrict__ zr, int n) {
  __shared__ int lcsr[ALCSR];
  __shared__ __align__(16) unsigned short lagg[FTILE][136];
  __shared__ float zpart[2][4][FTILE];
  const int t = threadIdx.x;
  const int node0 = blockIdx.x * FTILE;
  int last = node0 + FTILE - 1; if (last >= n) last = n - 1;
  const int s_begin = offs[node0];
  const int total = offs[last] + deg[last] - s_begin;   // contiguous: FTILE | NPB
  const bool useLds = (total <= ALCSR);
  if (useLds) {
    for (int k = t; k < total; k += 256) lcsr[k] = csr[s_begin + k];
  }
  __syncthreads();

  const int w = t >> 6, l = t & 63;
  {  // ---- gather phase: 2 passes of 4 nodes per wave ----
    const int g = l >> 4, j = l & 15;
    const unsigned short* xj = x + 8 * j;
    #pragma unroll
    for (int p = 0; p < 2; p++) {
      const int nrow = w * 8 + p * 4 + g;
      const int node = node0 + nrow;
      if (node < n) {
        const int lb = offs[node] - s_begin;
        const int d = deg[node];
        float ac[4][8];
        #pragma unroll
        for (int c = 0; c < 4; c++)
          #pragma unroll
          for (int q = 0; q < 8; q++) ac[c][q] = 0.f;

        auto accum = [&](int c, uint4 v) {
          const unsigned q0 = v.x, q1 = v.y, q2 = v.z, q3 = v.w;
          ac[c][0] += __uint_as_float(q0 << 16); ac[c][1] += __uint_as_float(q0 & 0xffff0000u);
          ac[c][2] += __uint_as_float(q1 << 16); ac[c][3] += __uint_as_float(q1 & 0xffff0000u);
          ac[c][4] += __uint_as_float(q2 << 16); ac[c][5] += __uint_as_float(q2 & 0xffff0000u);
          ac[c][6] += __uint_as_float(q3 << 16); ac[c][7] += __uint_as_float(q3 & 0xffff0000u);
        };
        int i = 0;
        if (useLds) {
          const int* eb = lcsr + lb;
          for (; i + 3 < d; i += 4) {
            uint4 v0 = *(const uint4*)(xj + (size_t)eb[i]     * HD);
            uint4 v1 = *(const uint4*)(xj + (size_t)eb[i + 1] * HD);
            uint4 v2 = *(const uint4*)(xj + (size_t)eb[i + 2] * HD);
            uint4 v3 = *(const uint4*)(xj + (size_t)eb[i + 3] * HD);
            accum(0, v0); accum(1, v1); accum(2, v2); accum(3, v3);
          }
          for (; i < d; i++) accum(i & 3, *(const uint4*)(xj + (size_t)eb[i] * HD));
        } else {
          const int* eb = csr + s_begin + lb;
          for (; i + 3 < d; i += 4) {
            uint4 v0 = *(const uint4*)(xj + (size_t)eb[i]     * HD);
            uint4 v1 = *(const uint4*)(xj + (size_t)eb[i + 1] * HD);
            uint4 v2 = *(const uint4*)(xj + (size_t)eb[i + 2] * HD);
            uint4 v3 = *(const uint4*)(xj + (size_t)eb[i + 3] * HD);
            accum(0, v0); accum(1, v1); accum(2, v2); accum(3, v3);
          }
          for (; i < d; i++) accum(i & 3, *(const uint4*)(xj + (size_t)eb[i] * HD));
        }
        const float id = inv_deg[node];
        uint4 o;
        unsigned* op = (unsigned*)&o;
        #pragma unroll
        for (int k = 0; k < 4; k++) {
          float lo = (ac[0][2*k]   + ac[1][2*k]   + ac[2][2*k]   + ac[3][2*k])   * id;
          float hi = (ac[0][2*k+1] + ac[1][2*k+1] + ac[2][2*k+1] + ac[3][2*k+1]) * id;
          op[k] = (unsigned)f2bf(lo) | ((unsigned)f2bf(hi) << 16);
        }
        *(uint4*)&lagg[nrow][j * 8] = o;
      } else {
        *(uint4*)&lagg[nrow][j * 8] = make_uint4(0, 0, 0, 0);
      }
    }
  }
  __syncthreads();

  // ---- MFMA phase: wave w owns col-frags 2w,2w+1 for both 16-row tiles ----
  const int lr = l & 15, lg = l >> 4;
  int ra0 = node0 + lr;      if (ra0 >= n) ra0 = n - 1;
  int ra1 = node0 + 16 + lr; if (ra1 >= n) ra1 = n - 1;
  const unsigned short* wbase = Wp + (size_t)lr * 32 + (size_t)lg * 8;
  const unsigned short* rbase0 = x + (size_t)ra0 * HD + 8 * lg;
  const unsigned short* rbase1 = x + (size_t)ra1 * HD + 8 * lg;

  f32x4 acc[2][2];   // [row-tile][col-frag]
  #pragma unroll
  for (int c = 0; c < 2; c++) {
    float bv = bias[(2 * w + c) * 16 + lr];
    acc[0][c] = (f32x4){bv, bv, bv, bv};
    acc[1][c] = (f32x4){bv, bv, bv, bv};
  }
  #pragma unroll
  for (int ks = 0; ks < 4; ks++) {
    bf16x8 a0 = *(const bf16x8*)&lagg[lr][lg * 8 + ks * 32];
    bf16x8 a1 = *(const bf16x8*)&lagg[16 + lr][lg * 8 + ks * 32];
    #pragma unroll
    for (int c = 0; c < 2; c++) {
      int cb = 2 * w + c;
      bf16x8 bfv = *(const bf16x8*)(wbase + (size_t)(ks * 128 + cb * 16) * 32);
      acc[0][c] = __builtin_amdgcn_mfma_f32_16x16x32_bf16(a0, bfv, acc[0][c], 0, 0, 0);
      acc[1][c] = __builtin_amdgcn_mfma_f32_16x16x32_bf16(a1, bfv, acc[1][c], 0, 0, 0);
    }
  }
  #pragma unroll
  for (int ks = 0; ks < 4; ks++) {
    bf16x8 a0 = *(const bf16x8*)(rbase0 + ks * 32);
    bf16x8 a1 = *(const bf16x8*)(rbase1 + ks * 32);
    #pragma unroll
    for (int c = 0; c < 2; c++) {
      int cb = 2 * w + c;
      bf16x8 bfv = *(const bf16x8*)(wbase + (size_t)((4 + ks) * 128 + cb * 16) * 32);
      acc[0][c] = __builtin_amdgcn_mfma_f32_16x16x32_bf16(a0, bfv, acc[0][c], 0, 0, 0);
      acc[1][c] = __builtin_amdgcn_mfma_f32_16x16x32_bf16(a1, bfv, acc[1][c], 0, 0, 0);
    }
  }

  if constexpr (!EMIT_Z) {
    #pragma unroll
    for (int rt = 0; rt < 2; rt++) {
      #pragma unroll
      for (int c = 0; c < 2; c++) {
        int cb = 2 * w + c;
        #pragma unroll
        for (int r = 0; r < 4; r++) {
          int node = node0 + rt * 16 + lg * 4 + r;
          if (node < n)
            out[(size_t)node * HD + cb * 16 + lr] = f2bf(lrelu(acc[rt][c][r]));
        }
      }
    }
  } else {
    float vl[2][4] = {{0.f,0.f,0.f,0.f},{0.f,0.f,0.f,0.f}};
    float vr[2][4] = {{0.f,0.f,0.f,0.f},{0.f,0.f,0.f,0.f}};
    #pragma unroll
    for (int c = 0; c < 2; c++) {
      int cb = 2 * w + c;
      float wlv = wl[cb * 16 + lr];
      float wrv = wr[cb * 16 + lr];
      #pragma unroll
      for (int rt = 0; rt < 2; rt++) {
        #pragma unroll
        for (int r = 0; r < 4; r++) {
          float x3 = lrelu(acc[rt][c][r]);
          vl[rt][r] += x3 * wlv;
          vr[rt][r] += x3 * wrv;
        }
      }
    }
    #pragma unroll
    for (int rt = 0; rt < 2; rt++) {
      #pragma unroll
      for (int r = 0; r < 4; r++) {
        #pragma unroll
        for (int d = 1; d < 16; d <<= 1) {
          vl[rt][r] += __shfl_xor(vl[rt][r], d, 64);
          vr[rt][r] += __shfl_xor(vr[rt][r], d, 64);
        }
      }
    }
    if (lr == 0) {
      #pragma unroll
      for (int rt = 0; rt < 2; rt++) {
        #pragma unroll
        for (int r = 0; r < 4; r++) {
          zpart[0][w][rt * 16 + lg * 4 + r] = vl[rt][r];
          zpart[1][w][rt * 16 + lg * 4 + r] = vr[rt][r];
        }
      }
    }
    __syncthreads();
    if (t < FTILE) {
      int node = node0 + t;
      if (node < n) {
        zl[node] = zpart[0][0][t] + zpart[0][1][t] + zpart[0][2][t] + zpart[0][3][t];
        zr[node] = zpart[1][0][t] + zpart[1][1][t] + zpart[1][2][t] + zpart[1][3][t];
      }
    }
  }
}

// ---------------- final: out = sigmoid(mean(zl) + zr + bl) ----------------
__global__ __launch_bounds__(256)
void zfinal_kernel(const float* __restrict__ zl, const float* __restrict__ zr,
                   const int* __restrict__ csr, const int* __restrict__ offs,
                   const int* __restrict__ deg, const float* __restrict__ inv_deg,
                   const float* __restrict__ bl, float* __restrict__ out, int n) {
  int i = blockIdx.x * 256 + threadIdx.x;
  if (i >= n) return;
  int s0 = offs[i], d = deg[i];
  float a = 0.f;
  #pragma unroll 4
  for (int e = 0; e < d; e++) a += zl[csr[s0 + e]];
  float s = a * inv_deg[i] + bl[0] + zr[i];
  out[i] = 1.0f / (1.0f + expf(-s));
}

extern "C" void kernel_launch(void* const* d_in, const int* in_sizes, int n_in,
                              void* d_out, int out_size, void* d_ws, size_t ws_size,
                              hipStream_t stream) {
  const float* x_gen  = (const float*)d_in[0];
  const float* x_load = (const float*)d_in[1];
  const float* x_or   = (const float*)d_in[2];
  const float* x_ex   = (const float*)d_in[3];
  const int*   edge   = (const int*)d_in[4];
  const int*   ptv    = (const int*)d_in[5];
  const float* Wg1  = (const float*)d_in[6],  *bg1  = (const float*)d_in[7];
  const float* Wg2  = (const float*)d_in[8],  *bg2  = (const float*)d_in[9];
  const float* Wld1 = (const float*)d_in[10], *bld1 = (const float*)d_in[11];
  const float* Wld2 = (const float*)d_in[12], *bld2 = (const float*)d_in[13];
  const float* Wor1 = (const float*)d_in[14], *bor1 = (const float*)d_in[15];
  const float* Wor2 = (const float*)d_in[16], *bor2 = (const float*)d_in[17];
  const float* Wex1 = (const float*)d_in[18], *bex1 = (const float*)d_in[19];
  const float* Wex2 = (const float*)d_in[20], *bex2 = (const float*)d_in[21];
  const float* Wl_h = (const float*)d_in[22], *bl_h = (const float*)d_in[23];
  const float* Wr_h = (const float*)d_in[24];
  const float* Wl_o = (const float*)d_in[25], *bl_o = (const float*)d_in[26];
  const float* Wr_o = (const float*)d_in[27];

  const int n_gen  = in_sizes[0] / 3;
  const int n_load = in_sizes[1] / 3;
  const int n_or   = in_sizes[2] / 6;
  const int n_ex   = in_sizes[3] / 6;
  const int nE     = in_sizes[4] / 2;
  const int N      = in_sizes[5];
  const int* esrc = edge;
  const int* edst = edge + nE;

  // padded segment geometry (each segment rounded to 64 rows)
  const int np0 = ((n_gen  + 63) / 64) * 64;
  const int np1 = ((n_load + 63) / 64) * 64;
  const int np2 = ((n_or   + 63) / 64) * 64;
  const int np3 = ((n_ex   + 63) / 64) * 64;
  const int NP  = np0 + np1 + np2 + np3;
  const int4 padCum    = make_int4(np0, np0 + np1, np0 + np1 + np2, NP);
  const int4 realStart = make_int4(0, n_gen, n_gen + n_load, n_gen + n_load + n_or);
  const int4 realCnt   = make_int4(n_gen, n_load, n_or, n_ex);

  const int NB = (N + NPB - 1) / NPB;   // buckets (<=256 for N<=131072)

  // ---- workspace layout (row-major bf16 activations) ----
  size_t NPel = (size_t)NP * HD;
  size_t nel  = (size_t)N * HD;
  unsigned short* b0 = (unsigned short*)d_ws;  // h1 (padded)
  unsigned short* b1 = b0 + NPel;              // x current
  unsigned short* b3 = b1 + nel;               // x next
  int*  gcnt = (int*)(b3 + nel);               // 256 ints
  int*  ebuf = gcnt + 256;                     // NB*CAP packed edges
  int*  csr  = ebuf + (size_t)NB * CAP;
  int*  offs = csr + (size_t)NB * CAP;
  int*  deg  = offs + N;
  float* inv_deg = (float*)(deg + N);
  float* zl = inv_deg + N;
  float* zr = zl + N;
  int*  invp = (int*)(zr + N);
  uintptr_t wp_addr = ((uintptr_t)(invp + N) + 15) & ~(uintptr_t)15;
  unsigned short* Wp = (unsigned short*)wp_addr;   // 4*16384 + 3*32768 bf16

  // ---- weight repack + invptv + gcnt zero (one launch) ----
  wprep_all_kernel<<<640, 256, 0, stream>>>(Wg2, Wld2, Wor2, Wex2, Wl_h, Wr_h, Wp,
                                            ptv, invp, gcnt, N);

  // ---- embeddings ----
  embed1_kernel<<<NP / 2, 256, 0, stream>>>(x_gen, x_load, x_or, x_ex,
                                            Wg1, bg1, Wld1, bld1, Wor1, bor1, Wex1, bex1,
                                            b0, padCum, realCnt);
  mfma_embed2_kernel<<<NP / 64, 256, 0, stream>>>(b0, Wp, bg2, bld2, bor2, bex2,
                                                  invp, b1, padCum, realStart, realCnt);

  // ---- CSR build (bucketed, LDS-local atomics) ----
  bucket_scatter_kernel<<<(nE + SCHUNK - 1) / SCHUNK, 256, 0, stream>>>(esrc, edst, gcnt, ebuf, nE);
  bucket_build_kernel<<<NB, 256, 0, stream>>>(ebuf, gcnt, csr, offs, deg, inv_deg, N);

  // ---- hidden SAGE layers (fused gather+combine) ----
  const int fGrid = (N + FTILE - 1) / FTILE;
  const unsigned short* WpC = Wp + 4 * 16384;
  unsigned short* xcur = b1;
  unsigned short* xnext = b3;
  for (int l = 0; l < 2; l++) {
    sage_fused_kernel<false><<<fGrid, 256, 0, stream>>>(
        xcur, csr, offs, deg, inv_deg, WpC + (size_t)l * 32768,
        bl_h + (size_t)l * HD, xnext, nullptr, nullptr, nullptr, nullptr, N);
    unsigned short* tmp = xcur; xcur = xnext; xnext = tmp;
  }
  // layer 3 fused with output projection (zl = x3.Wl_o, zr = x3.Wr_o)
  sage_fused_kernel<true><<<fGrid, 256, 0, stream>>>(
      xcur, csr, offs, deg, inv_deg, WpC + 2 * 32768,
      bl_h + 2 * HD, nullptr, Wl_o, Wr_o, zl, zr, N);

  // ---- final scalar aggregation + sigmoid ----
  zfinal_kernel<<<(N + 255) / 256, 256, 0, stream>>>(zl, zr, csr, offs, deg, inv_deg,
                                                     bl_o, (float*)d_out, N);
}

// Round 9
// 352.577 us; speedup vs baseline: 2.0353x; 2.0353x over previous
//
#include <hip/hip_runtime.h>
#include <hip/hip_bf16.h>
#include <math.h>

#define HD 128
#define NPB 512        // nodes per bucket
#define CAP 16384      // edge capacity per bucket (avg ~8163 -> 2x headroom)
#define SCHUNK 4096    // edges per scatter block
#define FTILE 32       // nodes per fused-layer block
#define ALCSR 1536     // staged csr entries per 32-node block (avg ~522)

typedef __attribute__((ext_vector_type(8))) short  bf16x8;
typedef __attribute__((ext_vector_type(4))) float  f32x4;

__device__ __forceinline__ float lrelu(float v) { return v > 0.0f ? v : 0.1f * v; }

__device__ __forceinline__ unsigned short f2bf(float f) {
  union { float f; unsigned u; } c; c.f = f;
  unsigned u = c.u + 0x7fffu + ((c.u >> 16) & 1u);   // RNE
  return (unsigned short)(u >> 16);
}
__device__ __forceinline__ float bf2f(unsigned short u) {
  return __uint_as_float((unsigned)u << 16);
}

// ---------------- embedding layer 1 (all types, padded node ids) ----------------
__global__ __launch_bounds__(256)
void embed1_kernel(const float* __restrict__ xg, const float* __restrict__ xl,
                   const float* __restrict__ xo, const float* __restrict__ xe,
                   const float* __restrict__ Wg, const float* __restrict__ bg,
                   const float* __restrict__ Wl, const float* __restrict__ bl,
                   const float* __restrict__ Wo, const float* __restrict__ bo,
                   const float* __restrict__ We, const float* __restrict__ be,
                   unsigned short* __restrict__ h1, int4 padCum, int4 realCnt) {
  int p = blockIdx.x * 2 + (threadIdx.x >> 7);
  if (p >= padCum.w) return;
  int j = threadIdx.x & 127;
  int typ = (p < padCum.x) ? 0 : (p < padCum.y) ? 1 : (p < padCum.z) ? 2 : 3;
  int padStart = (typ == 0) ? 0 : (typ == 1) ? padCum.x : (typ == 2) ? padCum.y : padCum.z;
  int cnt = (typ == 0) ? realCnt.x : (typ == 1) ? realCnt.y : (typ == 2) ? realCnt.z : realCnt.w;
  int loc = p - padStart;
  if (loc >= cnt) return;
  const float *x, *W, *bb; int IN;
  if (typ == 0)      { x = xg; W = Wg; bb = bg; IN = 3; }
  else if (typ == 1) { x = xl; W = Wl; bb = bl; IN = 3; }
  else if (typ == 2) { x = xo; W = Wo; bb = bo; IN = 6; }
  else               { x = xe; W = We; bb = be; IN = 6; }
  float acc = bb[j];
  for (int k = 0; k < IN; k++) acc += x[(size_t)loc * IN + k] * W[k * HD + j];
  h1[(size_t)p * HD + j] = f2bf(lrelu(acc));
}

// ---------------- weight repack + invptv + gcnt zero ----------------
__global__ __launch_bounds__(256)
void wprep_all_kernel(const float* __restrict__ Wg2, const float* __restrict__ Wld2,
                      const float* __restrict__ Wor2, const float* __restrict__ Wex2,
                      const float* __restrict__ Wl_h, const float* __restrict__ Wr_h,
                      unsigned short* __restrict__ Wp,
                      const int* __restrict__ ptv, int* __restrict__ inv,
                      int* __restrict__ gcnt, int n) {
  int tid = blockIdx.x * 256 + threadIdx.x;      // 10 * 16384 total
  if (tid < 256) gcnt[tid] = 0;
  if (tid < n) inv[ptv[tid]] = tid;
  int m = tid >> 14;
  int i = tid & 16383;
  const float* src; unsigned short* dst;
  switch (m) {
    case 0: src = Wg2;  dst = Wp;             break;
    case 1: src = Wld2; dst = Wp + 16384;     break;
    case 2: src = Wor2; dst = Wp + 2 * 16384; break;
    case 3: src = Wex2; dst = Wp + 3 * 16384; break;
    default: {
      int mm = m - 4; int l = mm >> 1; int isR = mm & 1;
      src = (isR ? Wr_h : Wl_h) + (size_t)l * 16384;
      dst = Wp + 4 * 16384 + (size_t)l * 32768 + (isR ? 16384 : 0);
    }
  }
  int k = i >> 7, j = i & 127;
  int ks = k >> 5, g = (k >> 3) & 3, b = k & 7;
  dst[((ks * 128 + j) * 4 + g) * 8 + b] = f2bf(src[i]);
}

// ---------------- embedding layer 2 (MFMA), row-major out via invp ----------------
__global__ __launch_bounds__(256)
void mfma_embed2_kernel(const unsigned short* __restrict__ h1,
                        const unsigned short* __restrict__ Wp,
                        const float* __restrict__ b_g, const float* __restrict__ b_ld,
                        const float* __restrict__ b_or, const float* __restrict__ b_ex,
                        const int* __restrict__ inv, unsigned short* __restrict__ out,
                        int4 padCum, int4 realStart, int4 realCnt) {
  const int t = threadIdx.x, w = t >> 6, l = t & 63;
  const int lr = l & 15, lg = l >> 4;
  const int prow0 = blockIdx.x * 64 + w * 16;
  int typ = (prow0 < padCum.x) ? 0 : (prow0 < padCum.y) ? 1 : (prow0 < padCum.z) ? 2 : 3;
  int padStart = (typ == 0) ? 0 : (typ == 1) ? padCum.x : (typ == 2) ? padCum.y : padCum.z;
  int rStart = (typ == 0) ? realStart.x : (typ == 1) ? realStart.y : (typ == 2) ? realStart.z : realStart.w;
  int cnt = (typ == 0) ? realCnt.x : (typ == 1) ? realCnt.y : (typ == 2) ? realCnt.z : realCnt.w;
  const float* bias = (typ == 0) ? b_g : (typ == 1) ? b_ld : (typ == 2) ? b_or : b_ex;

  int raLoc = prow0 + lr - padStart; if (raLoc >= cnt) raLoc = cnt - 1;
  const unsigned short* abase = h1 + (size_t)(padStart + raLoc) * HD + 8 * lg;
  const unsigned short* wbase = Wp + (size_t)typ * 16384 + lr * 32 + lg * 8;

  f32x4 acc[8];
  #pragma unroll
  for (int cb = 0; cb < 8; cb++) {
    float bv = bias[cb * 16 + lr];
    acc[cb] = (f32x4){bv, bv, bv, bv};
  }
  #pragma unroll
  for (int ks = 0; ks < 4; ks++) {
    bf16x8 af = *(const bf16x8*)(abase + ks * 32);
    #pragma unroll
    for (int cb = 0; cb < 8; cb++) {
      bf16x8 bfv = *(const bf16x8*)(wbase + (size_t)(ks * 128 + cb * 16) * 32);
      acc[cb] = __builtin_amdgcn_mfma_f32_16x16x32_bf16(af, bfv, acc[cb], 0, 0, 0);
    }
  }
  int tgt[4];
  #pragma unroll
  for (int r = 0; r < 4; r++) {
    int locRow = prow0 + lg * 4 + r - padStart;
    tgt[r] = (locRow < cnt) ? inv[rStart + locRow] : -1;
  }
  #pragma unroll
  for (int cb = 0; cb < 8; cb++) {
    #pragma unroll
    for (int r = 0; r < 4; r++) {
      if (tgt[r] >= 0)
        out[(size_t)tgt[r] * HD + cb * 16 + lr] = f2bf(lrelu(acc[cb][r]));
    }
  }
}

// ---------------- CSR build phase 1: bucket scatter (packed int) ----------------
__global__ __launch_bounds__(256)
void bucket_scatter_kernel(const int* __restrict__ esrc, const int* __restrict__ edst,
                           int* __restrict__ gcnt, int* __restrict__ ebuf, int nE) {
  __shared__ int cnt[256];
  __shared__ int cur[256];
  const int t = threadIdx.x;
  const int c0 = blockIdx.x * SCHUNK;
  int s_arr[16], d_arr[16];
  cnt[t] = 0;
  __syncthreads();
  #pragma unroll
  for (int k = 0; k < 16; k++) {
    int idx = c0 + k * 256 + t;
    if (idx < nE) {
      s_arr[k] = esrc[idx];
      int d = edst[idx];
      d_arr[k] = d;
      atomicAdd(&cnt[d >> 9], 1);
    } else d_arr[k] = -1;
  }
  __syncthreads();
  if (cnt[t] > 0) cur[t] = atomicAdd(&gcnt[t], cnt[t]);
  __syncthreads();
  #pragma unroll
  for (int k = 0; k < 16; k++) {
    if (d_arr[k] >= 0) {
      int b = d_arr[k] >> 9;
      int p = atomicAdd(&cur[b], 1);
      ebuf[(size_t)b * CAP + p] = (s_arr[k] << 9) | (d_arr[k] & 511);
    }
  }
}

__device__ __forceinline__ int wave_incl_scan(int v) {
  int lane = threadIdx.x & 63;
  #pragma unroll
  for (int d = 1; d < 64; d <<= 1) {
    int tv = __shfl_up(v, d, 64);
    if (lane >= d) v += tv;
  }
  return v;
}

// ---------------- CSR build phase 2: per-bucket local build ----------------
__global__ __launch_bounds__(256)
void bucket_build_kernel(const int* __restrict__ ebuf, const int* __restrict__ gcnt,
                         int* __restrict__ csr, int* __restrict__ offs,
                         int* __restrict__ deg, float* __restrict__ inv_deg, int n) {
  __shared__ int hist[512];
  __shared__ int offl[512];
  __shared__ int wsum[4];
  const int b = blockIdx.x, t = threadIdx.x;
  const int cnt = gcnt[b];
  const size_t ebase = (size_t)b * CAP;
  hist[t] = 0; hist[t + 256] = 0;
  __syncthreads();
  for (int i = t; i < cnt; i += 256) {
    int e = ebuf[ebase + i];
    atomicAdd(&hist[e & 511], 1);
  }
  __syncthreads();
  int a0 = hist[2 * t], a1 = hist[2 * t + 1];
  int s = a0 + a1;
  int incl = wave_incl_scan(s);
  int wid = t >> 6;
  if ((t & 63) == 63) wsum[wid] = incl;
  __syncthreads();
  int wbase = 0;
  for (int w_ = 0; w_ < wid; w_++) wbase += wsum[w_];
  int excl = wbase + incl - s;
  offl[2 * t] = excl;
  offl[2 * t + 1] = excl + a0;
  __syncthreads();
  const int d0 = b << 9;
  for (int i = t; i < 512; i += 256) {
    int g = d0 + i;
    if (g < n) {
      offs[g] = b * CAP + offl[i];
      int dg = hist[i];
      deg[g] = dg;
      inv_deg[g] = 1.0f / fmaxf((float)dg, 1.0f);
    }
  }
  __syncthreads();
  for (int i = t; i < cnt; i += 256) {
    int e = ebuf[ebase + i];
    int p = atomicAdd(&offl[e & 511], 1);
    csr[ebase + p] = ((unsigned)e) >> 9;
  }
}

// ---------------- fused SAGE layer: gather-mean + MFMA combine (32-node tile) ----------------
// Gather: round-7-proven inner loop (2-chain ILP, static float2 a0[4]/a1[4]),
// 2 passes of 4 nodes per wave. MFMA: 2 row-tiles; wave w owns col-frags
// 2w,2w+1 for BOTH tiles (each weight fragment loaded once, used twice).
template<bool EMIT_Z>
__global__ __launch_bounds__(256)
void sage_fused_kernel(const unsigned short* __restrict__ x, const int* __restrict__ csr,
                       const int* __restrict__ offs, const int* __restrict__ deg,
                       const float* __restrict__ inv_deg,
                       const unsigned short* __restrict__ Wp, const float* __restrict__ bias,
                       unsigned short* __restrict__ out,
                       const float* __restrict__ wl, const float* __restrict__ wr,
                       float* __restrict__ zl, float* __restrict__ zr, int n) {
  __shared__ int lcsr[ALCSR];
  __shared__ __align__(16) unsigned short lagg[FTILE][136];
  __shared__ float zpart[2][4][FTILE];
  const int t = threadIdx.x;
  const int node0 = blockIdx.x * FTILE;
  int last = node0 + FTILE - 1; if (last >= n) last = n - 1;
  const int s_begin = offs[node0];
  const int total = offs[last] + deg[last] - s_begin;   // contiguous: FTILE | NPB
  const bool useLds = (total <= ALCSR);
  if (useLds) {
    for (int k = t; k < total; k += 256) lcsr[k] = csr[s_begin + k];
  }
  __syncthreads();

  const int w = t >> 6, l = t & 63;
  {  // ---- gather phase: 2 passes of 4 nodes per wave (round-7 inner loop) ----
    const int g = l >> 4, j = l & 15;
    const unsigned short* xj = x + 8 * j;
    #pragma unroll
    for (int p = 0; p < 2; p++) {
      const int nrow = w * 8 + p * 4 + g;
      const int node = node0 + nrow;
      if (node < n) {
        const int lb = offs[node] - s_begin;
        const int d = deg[node];
        float2 a0[4] = {{0.f,0.f},{0.f,0.f},{0.f,0.f},{0.f,0.f}};
        float2 a1[4] = {{0.f,0.f},{0.f,0.f},{0.f,0.f},{0.f,0.f}};
        int i = 0;
        if (useLds) {
          for (; i + 1 < d; i += 2) {
            int e0 = lcsr[lb + i], e1 = lcsr[lb + i + 1];
            uint4 v0 = *(const uint4*)(xj + (size_t)e0 * HD);
            uint4 v1 = *(const uint4*)(xj + (size_t)e1 * HD);
            const unsigned w0[4] = {v0.x, v0.y, v0.z, v0.w};
            const unsigned w1[4] = {v1.x, v1.y, v1.z, v1.w};
            #pragma unroll
            for (int k = 0; k < 4; k++) {
              a0[k] = make_float2(a0[k].x + __uint_as_float(w0[k] << 16),
                                  a0[k].y + __uint_as_float(w0[k] & 0xffff0000u));
              a1[k] = make_float2(a1[k].x + __uint_as_float(w1[k] << 16),
                                  a1[k].y + __uint_as_float(w1[k] & 0xffff0000u));
            }
          }
          if (i < d) {
            int e0 = lcsr[lb + i];
            uint4 v0 = *(const uint4*)(xj + (size_t)e0 * HD);
            const unsigned w0[4] = {v0.x, v0.y, v0.z, v0.w};
            #pragma unroll
            for (int k = 0; k < 4; k++)
              a0[k] = make_float2(a0[k].x + __uint_as_float(w0[k] << 16),
                                  a0[k].y + __uint_as_float(w0[k] & 0xffff0000u));
          }
        } else {
          const int* gcsr = csr + s_begin + lb;
          for (; i + 1 < d; i += 2) {
            int e0 = gcsr[i], e1 = gcsr[i + 1];
            uint4 v0 = *(const uint4*)(xj + (size_t)e0 * HD);
            uint4 v1 = *(const uint4*)(xj + (size_t)e1 * HD);
            const unsigned w0[4] = {v0.x, v0.y, v0.z, v0.w};
            const unsigned w1[4] = {v1.x, v1.y, v1.z, v1.w};
            #pragma unroll
            for (int k = 0; k < 4; k++) {
              a0[k] = make_float2(a0[k].x + __uint_as_float(w0[k] << 16),
                                  a0[k].y + __uint_as_float(w0[k] & 0xffff0000u));
              a1[k] = make_float2(a1[k].x + __uint_as_float(w1[k] << 16),
                                  a1[k].y + __uint_as_float(w1[k] & 0xffff0000u));
            }
          }
          if (i < d) {
            int e0 = gcsr[i];
            uint4 v0 = *(const uint4*)(xj + (size_t)e0 * HD);
            const unsigned w0[4] = {v0.x, v0.y, v0.z, v0.w};
            #pragma unroll
            for (int k = 0; k < 4; k++)
              a0[k] = make_float2(a0[k].x + __uint_as_float(w0[k] << 16),
                                  a0[k].y + __uint_as_float(w0[k] & 0xffff0000u));
          }
        }
        const float id = inv_deg[node];
        uint4 o;
        unsigned* op = (unsigned*)&o;
        #pragma unroll
        for (int k = 0; k < 4; k++) {
          float lo = (a0[k].x + a1[k].x) * id;
          float hi = (a0[k].y + a1[k].y) * id;
          op[k] = (unsigned)f2bf(lo) | ((unsigned)f2bf(hi) << 16);
        }
        *(uint4*)&lagg[nrow][j * 8] = o;
      } else {
        *(uint4*)&lagg[nrow][j * 8] = make_uint4(0, 0, 0, 0);
      }
    }
  }
  __syncthreads();

  // ---- MFMA phase: wave w owns col-frags 2w,2w+1 for both 16-row tiles ----
  const int lr = l & 15, lg = l >> 4;
  int ra0 = node0 + lr;      if (ra0 >= n) ra0 = n - 1;
  int ra1 = node0 + 16 + lr; if (ra1 >= n) ra1 = n - 1;
  const unsigned short* wbase = Wp + (size_t)lr * 32 + (size_t)lg * 8;
  const unsigned short* rbase0 = x + (size_t)ra0 * HD + 8 * lg;
  const unsigned short* rbase1 = x + (size_t)ra1 * HD + 8 * lg;

  f32x4 acc[2][2];   // [row-tile][col-frag]
  #pragma unroll
  for (int c = 0; c < 2; c++) {
    float bv = bias[(2 * w + c) * 16 + lr];
    acc[0][c] = (f32x4){bv, bv, bv, bv};
    acc[1][c] = (f32x4){bv, bv, bv, bv};
  }
  #pragma unroll
  for (int ks = 0; ks < 4; ks++) {
    bf16x8 a0 = *(const bf16x8*)&lagg[lr][lg * 8 + ks * 32];
    bf16x8 a1 = *(const bf16x8*)&lagg[16 + lr][lg * 8 + ks * 32];
    #pragma unroll
    for (int c = 0; c < 2; c++) {
      int cb = 2 * w + c;
      bf16x8 bfv = *(const bf16x8*)(wbase + (size_t)(ks * 128 + cb * 16) * 32);
      acc[0][c] = __builtin_amdgcn_mfma_f32_16x16x32_bf16(a0, bfv, acc[0][c], 0, 0, 0);
      acc[1][c] = __builtin_amdgcn_mfma_f32_16x16x32_bf16(a1, bfv, acc[1][c], 0, 0, 0);
    }
  }
  #pragma unroll
  for (int ks = 0; ks < 4; ks++) {
    bf16x8 a0 = *(const bf16x8*)(rbase0 + ks * 32);
    bf16x8 a1 = *(const bf16x8*)(rbase1 + ks * 32);
    #pragma unroll
    for (int c = 0; c < 2; c++) {
      int cb = 2 * w + c;
      bf16x8 bfv = *(const bf16x8*)(wbase + (size_t)((4 + ks) * 128 + cb * 16) * 32);
      acc[0][c] = __builtin_amdgcn_mfma_f32_16x16x32_bf16(a0, bfv, acc[0][c], 0, 0, 0);
      acc[1][c] = __builtin_amdgcn_mfma_f32_16x16x32_bf16(a1, bfv, acc[1][c], 0, 0, 0);
    }
  }

  if constexpr (!EMIT_Z) {
    #pragma unroll
    for (int rt = 0; rt < 2; rt++) {
      #pragma unroll
      for (int c = 0; c < 2; c++) {
        int cb = 2 * w + c;
        #pragma unroll
        for (int r = 0; r < 4; r++) {
          int node = node0 + rt * 16 + lg * 4 + r;
          if (node < n)
            out[(size_t)node * HD + cb * 16 + lr] = f2bf(lrelu(acc[rt][c][r]));
        }
      }
    }
  } else {
    float vl0[4] = {0.f,0.f,0.f,0.f}, vl1[4] = {0.f,0.f,0.f,0.f};
    float vr0[4] = {0.f,0.f,0.f,0.f}, vr1[4] = {0.f,0.f,0.f,0.f};
    #pragma unroll
    for (int c = 0; c < 2; c++) {
      int cb = 2 * w + c;
      float wlv = wl[cb * 16 + lr];
      float wrv = wr[cb * 16 + lr];
      #pragma unroll
      for (int r = 0; r < 4; r++) {
        float x30 = lrelu(acc[0][c][r]);
        float x31 = lrelu(acc[1][c][r]);
        vl0[r] += x30 * wlv; vr0[r] += x30 * wrv;
        vl1[r] += x31 * wlv; vr1[r] += x31 * wrv;
      }
    }
    #pragma unroll
    for (int r = 0; r < 4; r++) {
      #pragma unroll
      for (int d = 1; d < 16; d <<= 1) {
        vl0[r] += __shfl_xor(vl0[r], d, 64);
        vr0[r] += __shfl_xor(vr0[r], d, 64);
        vl1[r] += __shfl_xor(vl1[r], d, 64);
        vr1[r] += __shfl_xor(vr1[r], d, 64);
      }
    }
    if (lr == 0) {
      #pragma unroll
      for (int r = 0; r < 4; r++) {
        zpart[0][w][lg * 4 + r] = vl0[r];
        zpart[1][w][lg * 4 + r] = vr0[r];
        zpart[0][w][16 + lg * 4 + r] = vl1[r];
        zpart[1][w][16 + lg * 4 + r] = vr1[r];
      }
    }
    __syncthreads();
    if (t < FTILE) {
      int node = node0 + t;
      if (node < n) {
        zl[node] = zpart[0][0][t] + zpart[0][1][t] + zpart[0][2][t] + zpart[0][3][t];
        zr[node] = zpart[1][0][t] + zpart[1][1][t] + zpart[1][2][t] + zpart[1][3][t];
      }
    }
  }
}

// ---------------- final: out = sigmoid(mean(zl) + zr + bl) ----------------
__global__ __launch_bounds__(256)
void zfinal_kernel(const float* __restrict__ zl, const float* __restrict__ zr,
                   const int* __restrict__ csr, const int* __restrict__ offs,
                   const int* __restrict__ deg, const float* __restrict__ inv_deg,
                   const float* __restrict__ bl, float* __restrict__ out, int n) {
  int i = blockIdx.x * 256 + threadIdx.x;
  if (i >= n) return;
  int s0 = offs[i], d = deg[i];
  float a = 0.f;
  #pragma unroll 4
  for (int e = 0; e < d; e++) a += zl[csr[s0 + e]];
  float s = a * inv_deg[i] + bl[0] + zr[i];
  out[i] = 1.0f / (1.0f + expf(-s));
}

extern "C" void kernel_launch(void* const* d_in, const int* in_sizes, int n_in,
                              void* d_out, int out_size, void* d_ws, size_t ws_size,
                              hipStream_t stream) {
  const float* x_gen  = (const float*)d_in[0];
  const float* x_load = (const float*)d_in[1];
  const float* x_or   = (const float*)d_in[2];
  const float* x_ex   = (const float*)d_in[3];
  const int*   edge   = (const int*)d_in[4];
  const int*   ptv    = (const int*)d_in[5];
  const float* Wg1  = (const float*)d_in[6],  *bg1  = (const float*)d_in[7];
  const float* Wg2  = (const float*)d_in[8],  *bg2  = (const float*)d_in[9];
  const float* Wld1 = (const float*)d_in[10], *bld1 = (const float*)d_in[11];
  const float* Wld2 = (const float*)d_in[12], *bld2 = (const float*)d_in[13];
  const float* Wor1 = (const float*)d_in[14], *bor1 = (const float*)d_in[15];
  const float* Wor2 = (const float*)d_in[16], *bor2 = (const float*)d_in[17];
  const float* Wex1 = (const float*)d_in[18], *bex1 = (const float*)d_in[19];
  const float* Wex2 = (const float*)d_in[20], *bex2 = (const float*)d_in[21];
  const float* Wl_h = (const float*)d_in[22], *bl_h = (const float*)d_in[23];
  const float* Wr_h = (const float*)d_in[24];
  const float* Wl_o = (const float*)d_in[25], *bl_o = (const float*)d_in[26];
  const float* Wr_o = (const float*)d_in[27];

  const int n_gen  = in_sizes[0] / 3;
  const int n_load = in_sizes[1] / 3;
  const int n_or   = in_sizes[2] / 6;
  const int n_ex   = in_sizes[3] / 6;
  const int nE     = in_sizes[4] / 2;
  const int N      = in_sizes[5];
  const int* esrc = edge;
  const int* edst = edge + nE;

  // padded segment geometry (each segment rounded to 64 rows)
  const int np0 = ((n_gen  + 63) / 64) * 64;
  const int np1 = ((n_load + 63) / 64) * 64;
  const int np2 = ((n_or   + 63) / 64) * 64;
  const int np3 = ((n_ex   + 63) / 64) * 64;
  const int NP  = np0 + np1 + np2 + np3;
  const int4 padCum    = make_int4(np0, np0 + np1, np0 + np1 + np2, NP);
  const int4 realStart = make_int4(0, n_gen, n_gen + n_load, n_gen + n_load + n_or);
  const int4 realCnt   = make_int4(n_gen, n_load, n_or, n_ex);

  const int NB = (N + NPB - 1) / NPB;   // buckets (<=256 for N<=131072)

  // ---- workspace layout (row-major bf16 activations) ----
  size_t NPel = (size_t)NP * HD;
  size_t nel  = (size_t)N * HD;
  unsigned short* b0 = (unsigned short*)d_ws;  // h1 (padded)
  unsigned short* b1 = b0 + NPel;              // x current
  unsigned short* b3 = b1 + nel;               // x next
  int*  gcnt = (int*)(b3 + nel);               // 256 ints
  int*  ebuf = gcnt + 256;                     // NB*CAP packed edges
  int*  csr  = ebuf + (size_t)NB * CAP;
  int*  offs = csr + (size_t)NB * CAP;
  int*  deg  = offs + N;
  float* inv_deg = (float*)(deg + N);
  float* zl = inv_deg + N;
  float* zr = zl + N;
  int*  invp = (int*)(zr + N);
  uintptr_t wp_addr = ((uintptr_t)(invp + N) + 15) & ~(uintptr_t)15;
  unsigned short* Wp = (unsigned short*)wp_addr;   // 4*16384 + 3*32768 bf16

  // ---- weight repack + invptv + gcnt zero (one launch) ----
  wprep_all_kernel<<<640, 256, 0, stream>>>(Wg2, Wld2, Wor2, Wex2, Wl_h, Wr_h, Wp,
                                            ptv, invp, gcnt, N);

  // ---- embeddings ----
  embed1_kernel<<<NP / 2, 256, 0, stream>>>(x_gen, x_load, x_or, x_ex,
                                            Wg1, bg1, Wld1, bld1, Wor1, bor1, Wex1, bex1,
                                            b0, padCum, realCnt);
  mfma_embed2_kernel<<<NP / 64, 256, 0, stream>>>(b0, Wp, bg2, bld2, bor2, bex2,
                                                  invp, b1, padCum, realStart, realCnt);

  // ---- CSR build (bucketed, LDS-local atomics) ----
  bucket_scatter_kernel<<<(nE + SCHUNK - 1) / SCHUNK, 256, 0, stream>>>(esrc, edst, gcnt, ebuf, nE);
  bucket_build_kernel<<<NB, 256, 0, stream>>>(ebuf, gcnt, csr, offs, deg, inv_deg, N);

  // ---- hidden SAGE layers (fused gather+combine) ----
  const int fGrid = (N + FTILE - 1) / FTILE;
  const unsigned short* WpC = Wp + 4 * 16384;
  unsigned short* xcur = b1;
  unsigned short* xnext = b3;
  for (int l = 0; l < 2; l++) {
    sage_fused_kernel<false><<<fGrid, 256, 0, stream>>>(
        xcur, csr, offs, deg, inv_deg, WpC + (size_t)l * 32768,
        bl_h + (size_t)l * HD, xnext, nullptr, nullptr, nullptr, nullptr, N);
    unsigned short* tmp = xcur; xcur = xnext; xnext = tmp;
  }
  // layer 3 fused with output projection (zl = x3.Wl_o, zr = x3.Wr_o)
  sage_fused_kernel<true><<<fGrid, 256, 0, stream>>>(
      xcur, csr, offs, deg, inv_deg, WpC + 2 * 32768,
      bl_h + 2 * HD, nullptr, Wl_o, Wr_o, zl, zr, N);

  // ---- final scalar aggregation + sigmoid ----
  zfinal_kernel<<<(N + 255) / 256, 256, 0, stream>>>(zl, zr, csr, offs, deg, inv_deg,
                                                     bl_o, (float*)d_out, N);
}

// Round 10
// 347.041 us; speedup vs baseline: 2.0677x; 1.0160x over previous
//
#include <hip/hip_runtime.h>
#include <hip/hip_bf16.h>
#include <math.h>

#define HD 128
#define NPB 512        // nodes per bucket
#define CAP 16384      // edge capacity per bucket (avg ~8163 -> 2x headroom)
#define SCHUNK 4096    // edges per scatter block
#define ALCSR 768      // staged csr entries per 16-node block (avg ~256)

typedef __attribute__((ext_vector_type(8))) short  bf16x8;
typedef __attribute__((ext_vector_type(4))) float  f32x4;

__device__ __forceinline__ float lrelu(float v) { return v > 0.0f ? v : 0.1f * v; }

__device__ __forceinline__ unsigned short f2bf(float f) {
  union { float f; unsigned u; } c; c.f = f;
  unsigned u = c.u + 0x7fffu + ((c.u >> 16) & 1u);   // RNE
  return (unsigned short)(u >> 16);
}
__device__ __forceinline__ float bf2f(unsigned short u) {
  return __uint_as_float((unsigned)u << 16);
}

// ---------------- embedding layer 1 (all types, padded node ids) ----------------
__global__ __launch_bounds__(256)
void embed1_kernel(const float* __restrict__ xg, const float* __restrict__ xl,
                   const float* __restrict__ xo, const float* __restrict__ xe,
                   const float* __restrict__ Wg, const float* __restrict__ bg,
                   const float* __restrict__ Wl, const float* __restrict__ bl,
                   const float* __restrict__ Wo, const float* __restrict__ bo,
                   const float* __restrict__ We, const float* __restrict__ be,
                   unsigned short* __restrict__ h1, int4 padCum, int4 realCnt) {
  int p = blockIdx.x * 2 + (threadIdx.x >> 7);
  if (p >= padCum.w) return;
  int j = threadIdx.x & 127;
  int typ = (p < padCum.x) ? 0 : (p < padCum.y) ? 1 : (p < padCum.z) ? 2 : 3;
  int padStart = (typ == 0) ? 0 : (typ == 1) ? padCum.x : (typ == 2) ? padCum.y : padCum.z;
  int cnt = (typ == 0) ? realCnt.x : (typ == 1) ? realCnt.y : (typ == 2) ? realCnt.z : realCnt.w;
  int loc = p - padStart;
  if (loc >= cnt) return;
  const float *x, *W, *bb; int IN;
  if (typ == 0)      { x = xg; W = Wg; bb = bg; IN = 3; }
  else if (typ == 1) { x = xl; W = Wl; bb = bl; IN = 3; }
  else if (typ == 2) { x = xo; W = Wo; bb = bo; IN = 6; }
  else               { x = xe; W = We; bb = be; IN = 6; }
  float acc = bb[j];
  for (int k = 0; k < IN; k++) acc += x[(size_t)loc * IN + k] * W[k * HD + j];
  h1[(size_t)p * HD + j] = f2bf(lrelu(acc));
}

// ---------------- weight repack + invptv + gcnt zero ----------------
__global__ __launch_bounds__(256)
void wprep_all_kernel(const float* __restrict__ Wg2, const float* __restrict__ Wld2,
                      const float* __restrict__ Wor2, const float* __restrict__ Wex2,
                      const float* __restrict__ Wl_h, const float* __restrict__ Wr_h,
                      unsigned short* __restrict__ Wp,
                      const int* __restrict__ ptv, int* __restrict__ inv,
                      int* __restrict__ gcnt, int n) {
  int tid = blockIdx.x * 256 + threadIdx.x;      // 10 * 16384 total
  if (tid < 256) gcnt[tid] = 0;
  if (tid < n) inv[ptv[tid]] = tid;
  int m = tid >> 14;
  int i = tid & 16383;
  const float* src; unsigned short* dst;
  switch (m) {
    case 0: src = Wg2;  dst = Wp;             break;
    case 1: src = Wld2; dst = Wp + 16384;     break;
    case 2: src = Wor2; dst = Wp + 2 * 16384; break;
    case 3: src = Wex2; dst = Wp + 3 * 16384; break;
    default: {
      int mm = m - 4; int l = mm >> 1; int isR = mm & 1;
      src = (isR ? Wr_h : Wl_h) + (size_t)l * 16384;
      dst = Wp + 4 * 16384 + (size_t)l * 32768 + (isR ? 16384 : 0);
    }
  }
  int k = i >> 7, j = i & 127;
  int ks = k >> 5, g = (k >> 3) & 3, b = k & 7;
  dst[((ks * 128 + j) * 4 + g) * 8 + b] = f2bf(src[i]);
}

// ---------------- embedding layer 2 (MFMA), row-major out via invp ----------------
__global__ __launch_bounds__(256)
void mfma_embed2_kernel(const unsigned short* __restrict__ h1,
                        const unsigned short* __restrict__ Wp,
                        const float* __restrict__ b_g, const float* __restrict__ b_ld,
                        const float* __restrict__ b_or, const float* __restrict__ b_ex,
                        const int* __restrict__ inv, unsigned short* __restrict__ out,
                        int4 padCum, int4 realStart, int4 realCnt) {
  const int t = threadIdx.x, w = t >> 6, l = t & 63;
  const int lr = l & 15, lg = l >> 4;
  const int prow0 = blockIdx.x * 64 + w * 16;
  int typ = (prow0 < padCum.x) ? 0 : (prow0 < padCum.y) ? 1 : (prow0 < padCum.z) ? 2 : 3;
  int padStart = (typ == 0) ? 0 : (typ == 1) ? padCum.x : (typ == 2) ? padCum.y : padCum.z;
  int rStart = (typ == 0) ? realStart.x : (typ == 1) ? realStart.y : (typ == 2) ? realStart.z : realStart.w;
  int cnt = (typ == 0) ? realCnt.x : (typ == 1) ? realCnt.y : (typ == 2) ? realCnt.z : realCnt.w;
  const float* bias = (typ == 0) ? b_g : (typ == 1) ? b_ld : (typ == 2) ? b_or : b_ex;

  int raLoc = prow0 + lr - padStart; if (raLoc >= cnt) raLoc = cnt - 1;
  const unsigned short* abase = h1 + (size_t)(padStart + raLoc) * HD + 8 * lg;
  const unsigned short* wbase = Wp + (size_t)typ * 16384 + lr * 32 + lg * 8;

  f32x4 acc[8];
  #pragma unroll
  for (int cb = 0; cb < 8; cb++) {
    float bv = bias[cb * 16 + lr];
    acc[cb] = (f32x4){bv, bv, bv, bv};
  }
  #pragma unroll
  for (int ks = 0; ks < 4; ks++) {
    bf16x8 af = *(const bf16x8*)(abase + ks * 32);
    #pragma unroll
    for (int cb = 0; cb < 8; cb++) {
      bf16x8 bfv = *(const bf16x8*)(wbase + (size_t)(ks * 128 + cb * 16) * 32);
      acc[cb] = __builtin_amdgcn_mfma_f32_16x16x32_bf16(af, bfv, acc[cb], 0, 0, 0);
    }
  }
  int tgt[4];
  #pragma unroll
  for (int r = 0; r < 4; r++) {
    int locRow = prow0 + lg * 4 + r - padStart;
    tgt[r] = (locRow < cnt) ? inv[rStart + locRow] : -1;
  }
  #pragma unroll
  for (int cb = 0; cb < 8; cb++) {
    #pragma unroll
    for (int r = 0; r < 4; r++) {
      if (tgt[r] >= 0)
        out[(size_t)tgt[r] * HD + cb * 16 + lr] = f2bf(lrelu(acc[cb][r]));
    }
  }
}

// ---------------- CSR build phase 1: bucket scatter (packed int) ----------------
__global__ __launch_bounds__(256)
void bucket_scatter_kernel(const int* __restrict__ esrc, const int* __restrict__ edst,
                           int* __restrict__ gcnt, int* __restrict__ ebuf, int nE) {
  __shared__ int cnt[256];
  __shared__ int cur[256];
  const int t = threadIdx.x;
  const int c0 = blockIdx.x * SCHUNK;
  int s_arr[16], d_arr[16];
  cnt[t] = 0;
  __syncthreads();
  #pragma unroll
  for (int k = 0; k < 16; k++) {
    int idx = c0 + k * 256 + t;
    if (idx < nE) {
      s_arr[k] = esrc[idx];
      int d = edst[idx];
      d_arr[k] = d;
      atomicAdd(&cnt[d >> 9], 1);
    } else d_arr[k] = -1;
  }
  __syncthreads();
  if (cnt[t] > 0) cur[t] = atomicAdd(&gcnt[t], cnt[t]);
  __syncthreads();
  #pragma unroll
  for (int k = 0; k < 16; k++) {
    if (d_arr[k] >= 0) {
      int b = d_arr[k] >> 9;
      int p = atomicAdd(&cur[b], 1);
      ebuf[(size_t)b * CAP + p] = (s_arr[k] << 9) | (d_arr[k] & 511);
    }
  }
}

__device__ __forceinline__ int wave_incl_scan(int v) {
  int lane = threadIdx.x & 63;
  #pragma unroll
  for (int d = 1; d < 64; d <<= 1) {
    int tv = __shfl_up(v, d, 64);
    if (lane >= d) v += tv;
  }
  return v;
}

// ---------------- CSR build phase 2: per-bucket local build ----------------
__global__ __launch_bounds__(256)
void bucket_build_kernel(const int* __restrict__ ebuf, const int* __restrict__ gcnt,
                         int* __restrict__ csr, int* __restrict__ offs,
                         int* __restrict__ deg, float* __restrict__ inv_deg, int n) {
  __shared__ int hist[512];
  __shared__ int offl[512];
  __shared__ int wsum[4];
  const int b = blockIdx.x, t = threadIdx.x;
  const int cnt = gcnt[b];
  const size_t ebase = (size_t)b * CAP;
  hist[t] = 0; hist[t + 256] = 0;
  __syncthreads();
  for (int i = t; i < cnt; i += 256) {
    int e = ebuf[ebase + i];
    atomicAdd(&hist[e & 511], 1);
  }
  __syncthreads();
  int a0 = hist[2 * t], a1 = hist[2 * t + 1];
  int s = a0 + a1;
  int incl = wave_incl_scan(s);
  int wid = t >> 6;
  if ((t & 63) == 63) wsum[wid] = incl;
  __syncthreads();
  int wbase = 0;
  for (int w_ = 0; w_ < wid; w_++) wbase += wsum[w_];
  int excl = wbase + incl - s;
  offl[2 * t] = excl;
  offl[2 * t + 1] = excl + a0;
  __syncthreads();
  const int d0 = b << 9;
  for (int i = t; i < 512; i += 256) {
    int g = d0 + i;
    if (g < n) {
      offs[g] = b * CAP + offl[i];
      int dg = hist[i];
      deg[g] = dg;
      inv_deg[g] = 1.0f / fmaxf((float)dg, 1.0f);
    }
  }
  __syncthreads();
  for (int i = t; i < cnt; i += 256) {
    int e = ebuf[ebase + i];
    int p = atomicAdd(&offl[e & 511], 1);
    csr[ebase + p] = ((unsigned)e) >> 9;
  }
}

// ---------------- fused SAGE layer: gather-mean + MFMA combine (16-node tile) ----------------
// Gather: 16 lanes x 16B per edge row (4 full 64B lines), 4-deep load pipeline
// into 2 static accumulator chains. Mean -> LDS (stride 136). MFMA: 4 waves
// split 8 col-frags of one 16-row tile over K=256 ([agg | root]).
template<bool EMIT_Z>
__global__ __launch_bounds__(256)
void sage_fused_kernel(const unsigned short* __restrict__ x, const int* __restrict__ csr,
                       const int* __restrict__ offs, const int* __restrict__ deg,
                       const float* __restrict__ inv_deg,
                       const unsigned short* __restrict__ Wp, const float* __restrict__ bias,
                       unsigned short* __restrict__ out,
                       const float* __restrict__ wl, const float* __restrict__ wr,
                       float* __restrict__ zl, float* __restrict__ zr, int n) {
  __shared__ int lcsr[ALCSR];
  __shared__ __align__(16) unsigned short lagg[16][136];
  __shared__ float zpart[2][4][16];
  const int t = threadIdx.x;
  const int node0 = blockIdx.x * 16;
  int last = node0 + 15; if (last >= n) last = n - 1;
  const int s_begin = offs[node0];
  const int total = offs[last] + deg[last] - s_begin;   // contiguous: 16 | NPB
  const bool useLds = (total <= ALCSR);
  if (useLds) {
    for (int k = t; k < total; k += 256) lcsr[k] = csr[s_begin + k];
  }
  __syncthreads();

  const int w = t >> 6, l = t & 63;
  {  // ---- gather phase: 4 nodes per wave, 4-deep load pipeline ----
    const int g = l >> 4, j = l & 15;
    const int node = node0 + w * 4 + g;
    if (node < n) {
      const unsigned short* xj = x + 8 * j;
      const int lb = offs[node] - s_begin;
      const int d = deg[node];
      float2 a0[4] = {{0.f,0.f},{0.f,0.f},{0.f,0.f},{0.f,0.f}};
      float2 a1[4] = {{0.f,0.f},{0.f,0.f},{0.f,0.f},{0.f,0.f}};
      auto acc4 = [](float2* A, uint4 v) {
        A[0].x += __uint_as_float(v.x << 16); A[0].y += __uint_as_float(v.x & 0xffff0000u);
        A[1].x += __uint_as_float(v.y << 16); A[1].y += __uint_as_float(v.y & 0xffff0000u);
        A[2].x += __uint_as_float(v.z << 16); A[2].y += __uint_as_float(v.z & 0xffff0000u);
        A[3].x += __uint_as_float(v.w << 16); A[3].y += __uint_as_float(v.w & 0xffff0000u);
      };
      int i = 0;
      if (useLds) {
        for (; i + 3 < d; i += 4) {
          int e0 = lcsr[lb + i], e1 = lcsr[lb + i + 1];
          int e2 = lcsr[lb + i + 2], e3 = lcsr[lb + i + 3];
          uint4 v0 = *(const uint4*)(xj + (size_t)e0 * HD);
          uint4 v1 = *(const uint4*)(xj + (size_t)e1 * HD);
          uint4 v2 = *(const uint4*)(xj + (size_t)e2 * HD);
          uint4 v3 = *(const uint4*)(xj + (size_t)e3 * HD);
          acc4(a0, v0); acc4(a1, v1); acc4(a0, v2); acc4(a1, v3);
        }
        if (i + 1 < d) {
          int e0 = lcsr[lb + i], e1 = lcsr[lb + i + 1];
          uint4 v0 = *(const uint4*)(xj + (size_t)e0 * HD);
          uint4 v1 = *(const uint4*)(xj + (size_t)e1 * HD);
          acc4(a0, v0); acc4(a1, v1);
          i += 2;
        }
        if (i < d) {
          int e0 = lcsr[lb + i];
          acc4(a0, *(const uint4*)(xj + (size_t)e0 * HD));
        }
      } else {
        const int* gcsr = csr + s_begin + lb;
        for (; i + 3 < d; i += 4) {
          int e0 = gcsr[i], e1 = gcsr[i + 1], e2 = gcsr[i + 2], e3 = gcsr[i + 3];
          uint4 v0 = *(const uint4*)(xj + (size_t)e0 * HD);
          uint4 v1 = *(const uint4*)(xj + (size_t)e1 * HD);
          uint4 v2 = *(const uint4*)(xj + (size_t)e2 * HD);
          uint4 v3 = *(const uint4*)(xj + (size_t)e3 * HD);
          acc4(a0, v0); acc4(a1, v1); acc4(a0, v2); acc4(a1, v3);
        }
        if (i + 1 < d) {
          int e0 = gcsr[i], e1 = gcsr[i + 1];
          uint4 v0 = *(const uint4*)(xj + (size_t)e0 * HD);
          uint4 v1 = *(const uint4*)(xj + (size_t)e1 * HD);
          acc4(a0, v0); acc4(a1, v1);
          i += 2;
        }
        if (i < d) {
          int e0 = gcsr[i];
          acc4(a0, *(const uint4*)(xj + (size_t)e0 * HD));
        }
      }
      const float id = inv_deg[node];
      uint4 o;
      unsigned* op = (unsigned*)&o;
      #pragma unroll
      for (int k = 0; k < 4; k++) {
        float lo = (a0[k].x + a1[k].x) * id;
        float hi = (a0[k].y + a1[k].y) * id;
        op[k] = (unsigned)f2bf(lo) | ((unsigned)f2bf(hi) << 16);
      }
      *(uint4*)&lagg[w * 4 + g][j * 8] = o;
    } else {
      *(uint4*)&lagg[w * 4 + g][j * 8] = make_uint4(0, 0, 0, 0);
    }
  }
  __syncthreads();

  // ---- MFMA phase: wave w owns col-frags 2w, 2w+1 ----
  const int lr = l & 15, lg = l >> 4;
  int ra = node0 + lr; if (ra >= n) ra = n - 1;
  const unsigned short* wbase = Wp + (size_t)lr * 32 + (size_t)lg * 8;
  const unsigned short* rbase = x + (size_t)ra * HD + 8 * lg;

  f32x4 acc[2];
  #pragma unroll
  for (int c = 0; c < 2; c++) {
    float bv = bias[(2 * w + c) * 16 + lr];
    acc[c] = (f32x4){bv, bv, bv, bv};
  }
  #pragma unroll
  for (int ks = 0; ks < 4; ks++) {
    bf16x8 af = *(const bf16x8*)&lagg[lr][lg * 8 + ks * 32];
    #pragma unroll
    for (int c = 0; c < 2; c++) {
      int cb = 2 * w + c;
      bf16x8 bfv = *(const bf16x8*)(wbase + (size_t)(ks * 128 + cb * 16) * 32);
      acc[c] = __builtin_amdgcn_mfma_f32_16x16x32_bf16(af, bfv, acc[c], 0, 0, 0);
    }
  }
  #pragma unroll
  for (int ks = 0; ks < 4; ks++) {
    bf16x8 af = *(const bf16x8*)(rbase + ks * 32);
    #pragma unroll
    for (int c = 0; c < 2; c++) {
      int cb = 2 * w + c;
      bf16x8 bfv = *(const bf16x8*)(wbase + (size_t)((4 + ks) * 128 + cb * 16) * 32);
      acc[c] = __builtin_amdgcn_mfma_f32_16x16x32_bf16(af, bfv, acc[c], 0, 0, 0);
    }
  }

  if constexpr (!EMIT_Z) {
    #pragma unroll
    for (int c = 0; c < 2; c++) {
      int cb = 2 * w + c;
      #pragma unroll
      for (int r = 0; r < 4; r++) {
        int node = node0 + lg * 4 + r;
        if (node < n)
          out[(size_t)node * HD + cb * 16 + lr] = f2bf(lrelu(acc[c][r]));
      }
    }
  } else {
    float vl[4] = {0.f, 0.f, 0.f, 0.f}, vr[4] = {0.f, 0.f, 0.f, 0.f};
    #pragma unroll
    for (int c = 0; c < 2; c++) {
      int cb = 2 * w + c;
      float wlv = wl[cb * 16 + lr];
      float wrv = wr[cb * 16 + lr];
      #pragma unroll
      for (int r = 0; r < 4; r++) {
        float x3 = lrelu(acc[c][r]);
        vl[r] += x3 * wlv;
        vr[r] += x3 * wrv;
      }
    }
    #pragma unroll
    for (int r = 0; r < 4; r++) {
      #pragma unroll
      for (int d = 1; d < 16; d <<= 1) {
        vl[r] += __shfl_xor(vl[r], d, 64);
        vr[r] += __shfl_xor(vr[r], d, 64);
      }
    }
    if (lr == 0) {
      #pragma unroll
      for (int r = 0; r < 4; r++) {
        zpart[0][w][lg * 4 + r] = vl[r];
        zpart[1][w][lg * 4 + r] = vr[r];
      }
    }
    __syncthreads();
    if (t < 16) {
      int node = node0 + t;
      if (node < n) {
        zl[node] = zpart[0][0][t] + zpart[0][1][t] + zpart[0][2][t] + zpart[0][3][t];
        zr[node] = zpart[1][0][t] + zpart[1][1][t] + zpart[1][2][t] + zpart[1][3][t];
      }
    }
  }
}

// ---------------- final: out = sigmoid(mean(zl) + zr + bl) ----------------
__global__ __launch_bounds__(256)
void zfinal_kernel(const float* __restrict__ zl, const float* __restrict__ zr,
                   const int* __restrict__ csr, const int* __restrict__ offs,
                   const int* __restrict__ deg, const float* __restrict__ inv_deg,
                   const float* __restrict__ bl, float* __restrict__ out, int n) {
  int i = blockIdx.x * 256 + threadIdx.x;
  if (i >= n) return;
  int s0 = offs[i], d = deg[i];
  float a = 0.f;
  #pragma unroll 4
  for (int e = 0; e < d; e++) a += zl[csr[s0 + e]];
  float s = a * inv_deg[i] + bl[0] + zr[i];
  out[i] = 1.0f / (1.0f + expf(-s));
}

extern "C" void kernel_launch(void* const* d_in, const int* in_sizes, int n_in,
                              void* d_out, int out_size, void* d_ws, size_t ws_size,
                              hipStream_t stream) {
  const float* x_gen  = (const float*)d_in[0];
  const float* x_load = (const float*)d_in[1];
  const float* x_or   = (const float*)d_in[2];
  const float* x_ex   = (const float*)d_in[3];
  const int*   edge   = (const int*)d_in[4];
  const int*   ptv    = (const int*)d_in[5];
  const float* Wg1  = (const float*)d_in[6],  *bg1  = (const float*)d_in[7];
  const float* Wg2  = (const float*)d_in[8],  *bg2  = (const float*)d_in[9];
  const float* Wld1 = (const float*)d_in[10], *bld1 = (const float*)d_in[11];
  const float* Wld2 = (const float*)d_in[12], *bld2 = (const float*)d_in[13];
  const float* Wor1 = (const float*)d_in[14], *bor1 = (const float*)d_in[15];
  const float* Wor2 = (const float*)d_in[16], *bor2 = (const float*)d_in[17];
  const float* Wex1 = (const float*)d_in[18], *bex1 = (const float*)d_in[19];
  const float* Wex2 = (const float*)d_in[20], *bex2 = (const float*)d_in[21];
  const float* Wl_h = (const float*)d_in[22], *bl_h = (const float*)d_in[23];
  const float* Wr_h = (const float*)d_in[24];
  const float* Wl_o = (const float*)d_in[25], *bl_o = (const float*)d_in[26];
  const float* Wr_o = (const float*)d_in[27];

  const int n_gen  = in_sizes[0] / 3;
  const int n_load = in_sizes[1] / 3;
  const int n_or   = in_sizes[2] / 6;
  const int n_ex   = in_sizes[3] / 6;
  const int nE     = in_sizes[4] / 2;
  const int N      = in_sizes[5];
  const int* esrc = edge;
  const int* edst = edge + nE;

  // padded segment geometry (each segment rounded to 64 rows)
  const int np0 = ((n_gen  + 63) / 64) * 64;
  const int np1 = ((n_load + 63) / 64) * 64;
  const int np2 = ((n_or   + 63) / 64) * 64;
  const int np3 = ((n_ex   + 63) / 64) * 64;
  const int NP  = np0 + np1 + np2 + np3;
  const int4 padCum    = make_int4(np0, np0 + np1, np0 + np1 + np2, NP);
  const int4 realStart = make_int4(0, n_gen, n_gen + n_load, n_gen + n_load + n_or);
  const int4 realCnt   = make_int4(n_gen, n_load, n_or, n_ex);

  const int NB = (N + NPB - 1) / NPB;   // buckets (<=256 for N<=131072)

  // ---- workspace layout (row-major bf16 activations) ----
  size_t NPel = (size_t)NP * HD;
  size_t nel  = (size_t)N * HD;
  unsigned short* b0 = (unsigned short*)d_ws;  // h1 (padded)
  unsigned short* b1 = b0 + NPel;              // x current
  unsigned short* b3 = b1 + nel;               // x next
  int*  gcnt = (int*)(b3 + nel);               // 256 ints
  int*  ebuf = gcnt + 256;                     // NB*CAP packed edges
  int*  csr  = ebuf + (size_t)NB * CAP;
  int*  offs = csr + (size_t)NB * CAP;
  int*  deg  = offs + N;
  float* inv_deg = (float*)(deg + N);
  float* zl = inv_deg + N;
  float* zr = zl + N;
  int*  invp = (int*)(zr + N);
  uintptr_t wp_addr = ((uintptr_t)(invp + N) + 15) & ~(uintptr_t)15;
  unsigned short* Wp = (unsigned short*)wp_addr;   // 4*16384 + 3*32768 bf16

  // ---- weight repack + invptv + gcnt zero (one launch) ----
  wprep_all_kernel<<<640, 256, 0, stream>>>(Wg2, Wld2, Wor2, Wex2, Wl_h, Wr_h, Wp,
                                            ptv, invp, gcnt, N);

  // ---- embeddings ----
  embed1_kernel<<<NP / 2, 256, 0, stream>>>(x_gen, x_load, x_or, x_ex,
                                            Wg1, bg1, Wld1, bld1, Wor1, bor1, Wex1, bex1,
                                            b0, padCum, realCnt);
  mfma_embed2_kernel<<<NP / 64, 256, 0, stream>>>(b0, Wp, bg2, bld2, bor2, bex2,
                                                  invp, b1, padCum, realStart, realCnt);

  // ---- CSR build (bucketed, LDS-local atomics) ----
  bucket_scatter_kernel<<<(nE + SCHUNK - 1) / SCHUNK, 256, 0, stream>>>(esrc, edst, gcnt, ebuf, nE);
  bucket_build_kernel<<<NB, 256, 0, stream>>>(ebuf, gcnt, csr, offs, deg, inv_deg, N);

  // ---- hidden SAGE layers (fused gather+combine) ----
  const int fGrid = (N + 15) / 16;
  const unsigned short* WpC = Wp + 4 * 16384;
  unsigned short* xcur = b1;
  unsigned short* xnext = b3;
  for (int l = 0; l < 2; l++) {
    sage_fused_kernel<false><<<fGrid, 256, 0, stream>>>(
        xcur, csr, offs, deg, inv_deg, WpC + (size_t)l * 32768,
        bl_h + (size_t)l * HD, xnext, nullptr, nullptr, nullptr, nullptr, N);
    unsigned short* tmp = xcur; xcur = xnext; xnext = tmp;
  }
  // layer 3 fused with output projection (zl = x3.Wl_o, zr = x3.Wr_o)
  sage_fused_kernel<true><<<fGrid, 256, 0, stream>>>(
      xcur, csr, offs, deg, inv_deg, WpC + 2 * 32768,
      bl_h + 2 * HD, nullptr, Wl_o, Wr_o, zl, zr, N);

  // ---- final scalar aggregation + sigmoid ----
  zfinal_kernel<<<(N + 255) / 256, 256, 0, stream>>>(zl, zr, csr, offs, deg, inv_deg,
                                                     bl_o, (float*)d_out, N);
}

// Round 11
// 331.111 us; speedup vs baseline: 2.1672x; 1.0481x over previous
//
#include <hip/hip_runtime.h>
#include <hip/hip_bf16.h>
#include <hip/hip_fp16.h>
#include <math.h>

#define HD 128
#define NPB 512        // nodes per bucket
#define CAP 16384      // edge capacity per bucket (avg ~8163 -> 2x headroom)
#define SCHUNK 4096    // edges per scatter block
#define ALCSR 768      // staged csr entries per 16-node block (avg ~256)

typedef __attribute__((ext_vector_type(8))) short  bf16x8;
typedef __attribute__((ext_vector_type(4))) float  f32x4;

__device__ __forceinline__ float lrelu(float v) { return v > 0.0f ? v : 0.1f * v; }

__device__ __forceinline__ unsigned short f2bf(float f) {
  union { float f; unsigned u; } c; c.f = f;
  unsigned u = c.u + 0x7fffu + ((c.u >> 16) & 1u);   // RNE
  return (unsigned short)(u >> 16);
}
__device__ __forceinline__ float bf2f(unsigned short u) {
  return __uint_as_float((unsigned)u << 16);
}
// fp8 e5m2 = top byte of fp16 (RNE twice: f32->f16->e5m2)
__device__ __forceinline__ unsigned char f2e5m2(float f) {
  unsigned short h = __half_as_ushort(__float2half(f));
  h = (unsigned short)(h + 0x7f + ((h >> 8) & 1));
  return (unsigned char)(h >> 8);
}
__device__ __forceinline__ float e5m2hi2f(unsigned u) {   // u = byte<<8 (low 16 bits)
  return __half2float(__ushort_as_half((unsigned short)u));
}

// ---------------- embedding layer 1 (all types, padded node ids) ----------------
__global__ __launch_bounds__(256)
void embed1_kernel(const float* __restrict__ xg, const float* __restrict__ xl,
                   const float* __restrict__ xo, const float* __restrict__ xe,
                   const float* __restrict__ Wg, const float* __restrict__ bg,
                   const float* __restrict__ Wl, const float* __restrict__ bl,
                   const float* __restrict__ Wo, const float* __restrict__ bo,
                   const float* __restrict__ We, const float* __restrict__ be,
                   unsigned short* __restrict__ h1, int4 padCum, int4 realCnt) {
  int p = blockIdx.x * 2 + (threadIdx.x >> 7);
  if (p >= padCum.w) return;
  int j = threadIdx.x & 127;
  int typ = (p < padCum.x) ? 0 : (p < padCum.y) ? 1 : (p < padCum.z) ? 2 : 3;
  int padStart = (typ == 0) ? 0 : (typ == 1) ? padCum.x : (typ == 2) ? padCum.y : padCum.z;
  int cnt = (typ == 0) ? realCnt.x : (typ == 1) ? realCnt.y : (typ == 2) ? realCnt.z : realCnt.w;
  int loc = p - padStart;
  if (loc >= cnt) return;
  const float *x, *W, *bb; int IN;
  if (typ == 0)      { x = xg; W = Wg; bb = bg; IN = 3; }
  else if (typ == 1) { x = xl; W = Wl; bb = bl; IN = 3; }
  else if (typ == 2) { x = xo; W = Wo; bb = bo; IN = 6; }
  else               { x = xe; W = We; bb = be; IN = 6; }
  float acc = bb[j];
  for (int k = 0; k < IN; k++) acc += x[(size_t)loc * IN + k] * W[k * HD + j];
  h1[(size_t)p * HD + j] = f2bf(lrelu(acc));
}

// ---------------- weight repack + invptv + gcnt zero ----------------
__global__ __launch_bounds__(256)
void wprep_all_kernel(const float* __restrict__ Wg2, const float* __restrict__ Wld2,
                      const float* __restrict__ Wor2, const float* __restrict__ Wex2,
                      const float* __restrict__ Wl_h, const float* __restrict__ Wr_h,
                      unsigned short* __restrict__ Wp,
                      const int* __restrict__ ptv, int* __restrict__ inv,
                      int* __restrict__ gcnt, int n) {
  int tid = blockIdx.x * 256 + threadIdx.x;      // 10 * 16384 total
  if (tid < 256) gcnt[tid] = 0;
  if (tid < n) inv[ptv[tid]] = tid;
  int m = tid >> 14;
  int i = tid & 16383;
  const float* src; unsigned short* dst;
  switch (m) {
    case 0: src = Wg2;  dst = Wp;             break;
    case 1: src = Wld2; dst = Wp + 16384;     break;
    case 2: src = Wor2; dst = Wp + 2 * 16384; break;
    case 3: src = Wex2; dst = Wp + 3 * 16384; break;
    default: {
      int mm = m - 4; int l = mm >> 1; int isR = mm & 1;
      src = (isR ? Wr_h : Wl_h) + (size_t)l * 16384;
      dst = Wp + 4 * 16384 + (size_t)l * 32768 + (isR ? 16384 : 0);
    }
  }
  int k = i >> 7, j = i & 127;
  int ks = k >> 5, g = (k >> 3) & 3, b = k & 7;
  dst[((ks * 128 + j) * 4 + g) * 8 + b] = f2bf(src[i]);
}

// ---------------- embedding layer 2 (MFMA), row-major out via invp ----------------
__global__ __launch_bounds__(256)
void mfma_embed2_kernel(const unsigned short* __restrict__ h1,
                        const unsigned short* __restrict__ Wp,
                        const float* __restrict__ b_g, const float* __restrict__ b_ld,
                        const float* __restrict__ b_or, const float* __restrict__ b_ex,
                        const int* __restrict__ inv, unsigned short* __restrict__ out,
                        int4 padCum, int4 realStart, int4 realCnt) {
  const int t = threadIdx.x, w = t >> 6, l = t & 63;
  const int lr = l & 15, lg = l >> 4;
  const int prow0 = blockIdx.x * 64 + w * 16;
  int typ = (prow0 < padCum.x) ? 0 : (prow0 < padCum.y) ? 1 : (prow0 < padCum.z) ? 2 : 3;
  int padStart = (typ == 0) ? 0 : (typ == 1) ? padCum.x : (typ == 2) ? padCum.y : padCum.z;
  int rStart = (typ == 0) ? realStart.x : (typ == 1) ? realStart.y : (typ == 2) ? realStart.z : realStart.w;
  int cnt = (typ == 0) ? realCnt.x : (typ == 1) ? realCnt.y : (typ == 2) ? realCnt.z : realCnt.w;
  const float* bias = (typ == 0) ? b_g : (typ == 1) ? b_ld : (typ == 2) ? b_or : b_ex;

  int raLoc = prow0 + lr - padStart; if (raLoc >= cnt) raLoc = cnt - 1;
  const unsigned short* abase = h1 + (size_t)(padStart + raLoc) * HD + 8 * lg;
  const unsigned short* wbase = Wp + (size_t)typ * 16384 + lr * 32 + lg * 8;

  f32x4 acc[8];
  #pragma unroll
  for (int cb = 0; cb < 8; cb++) {
    float bv = bias[cb * 16 + lr];
    acc[cb] = (f32x4){bv, bv, bv, bv};
  }
  #pragma unroll
  for (int ks = 0; ks < 4; ks++) {
    bf16x8 af = *(const bf16x8*)(abase + ks * 32);
    #pragma unroll
    for (int cb = 0; cb < 8; cb++) {
      bf16x8 bfv = *(const bf16x8*)(wbase + (size_t)(ks * 128 + cb * 16) * 32);
      acc[cb] = __builtin_amdgcn_mfma_f32_16x16x32_bf16(af, bfv, acc[cb], 0, 0, 0);
    }
  }
  int tgt[4];
  #pragma unroll
  for (int r = 0; r < 4; r++) {
    int locRow = prow0 + lg * 4 + r - padStart;
    tgt[r] = (locRow < cnt) ? inv[rStart + locRow] : -1;
  }
  #pragma unroll
  for (int cb = 0; cb < 8; cb++) {
    #pragma unroll
    for (int r = 0; r < 4; r++) {
      if (tgt[r] >= 0)
        out[(size_t)tgt[r] * HD + cb * 16 + lr] = f2bf(lrelu(acc[cb][r]));
    }
  }
}

// ---------------- bf16 row-major -> fp8 e5m2 copy (one-time, coalesced) ----------------
__global__ __launch_bounds__(256)
void bf2f8_kernel(const unsigned short* __restrict__ in, unsigned char* __restrict__ out, int n8) {
  int idx = blockIdx.x * 256 + threadIdx.x;   // one thread per 8 elements
  if (idx >= n8) return;
  uint4 v = *(const uint4*)(in + (size_t)idx * 8);
  unsigned char b0 = f2e5m2(__uint_as_float(v.x << 16));
  unsigned char b1 = f2e5m2(__uint_as_float(v.x & 0xffff0000u));
  unsigned char b2 = f2e5m2(__uint_as_float(v.y << 16));
  unsigned char b3 = f2e5m2(__uint_as_float(v.y & 0xffff0000u));
  unsigned char b4 = f2e5m2(__uint_as_float(v.z << 16));
  unsigned char b5 = f2e5m2(__uint_as_float(v.z & 0xffff0000u));
  unsigned char b6 = f2e5m2(__uint_as_float(v.w << 16));
  unsigned char b7 = f2e5m2(__uint_as_float(v.w & 0xffff0000u));
  uint2 o;
  o.x = (unsigned)b0 | ((unsigned)b1 << 8) | ((unsigned)b2 << 16) | ((unsigned)b3 << 24);
  o.y = (unsigned)b4 | ((unsigned)b5 << 8) | ((unsigned)b6 << 16) | ((unsigned)b7 << 24);
  *(uint2*)(out + (size_t)idx * 8) = o;
}

// ---------------- CSR build phase 1: bucket scatter (packed int) ----------------
__global__ __launch_bounds__(256)
void bucket_scatter_kernel(const int* __restrict__ esrc, const int* __restrict__ edst,
                           int* __restrict__ gcnt, int* __restrict__ ebuf, int nE) {
  __shared__ int cnt[256];
  __shared__ int cur[256];
  const int t = threadIdx.x;
  const int c0 = blockIdx.x * SCHUNK;
  int s_arr[16], d_arr[16];
  cnt[t] = 0;
  __syncthreads();
  #pragma unroll
  for (int k = 0; k < 16; k++) {
    int idx = c0 + k * 256 + t;
    if (idx < nE) {
      s_arr[k] = esrc[idx];
      int d = edst[idx];
      d_arr[k] = d;
      atomicAdd(&cnt[d >> 9], 1);
    } else d_arr[k] = -1;
  }
  __syncthreads();
  if (cnt[t] > 0) cur[t] = atomicAdd(&gcnt[t], cnt[t]);
  __syncthreads();
  #pragma unroll
  for (int k = 0; k < 16; k++) {
    if (d_arr[k] >= 0) {
      int b = d_arr[k] >> 9;
      int p = atomicAdd(&cur[b], 1);
      ebuf[(size_t)b * CAP + p] = (s_arr[k] << 9) | (d_arr[k] & 511);
    }
  }
}

__device__ __forceinline__ int wave_incl_scan(int v) {
  int lane = threadIdx.x & 63;
  #pragma unroll
  for (int d = 1; d < 64; d <<= 1) {
    int tv = __shfl_up(v, d, 64);
    if (lane >= d) v += tv;
  }
  return v;
}

// ---------------- CSR build phase 2: per-bucket local build ----------------
__global__ __launch_bounds__(256)
void bucket_build_kernel(const int* __restrict__ ebuf, const int* __restrict__ gcnt,
                         int* __restrict__ csr, int* __restrict__ offs,
                         int* __restrict__ deg, float* __restrict__ inv_deg, int n) {
  __shared__ int hist[512];
  __shared__ int offl[512];
  __shared__ int wsum[4];
  const int b = blockIdx.x, t = threadIdx.x;
  const int cnt = gcnt[b];
  const size_t ebase = (size_t)b * CAP;
  hist[t] = 0; hist[t + 256] = 0;
  __syncthreads();
  for (int i = t; i < cnt; i += 256) {
    int e = ebuf[ebase + i];
    atomicAdd(&hist[e & 511], 1);
  }
  __syncthreads();
  int a0 = hist[2 * t], a1 = hist[2 * t + 1];
  int s = a0 + a1;
  int incl = wave_incl_scan(s);
  int wid = t >> 6;
  if ((t & 63) == 63) wsum[wid] = incl;
  __syncthreads();
  int wbase = 0;
  for (int w_ = 0; w_ < wid; w_++) wbase += wsum[w_];
  int excl = wbase + incl - s;
  offl[2 * t] = excl;
  offl[2 * t + 1] = excl + a0;
  __syncthreads();
  const int d0 = b << 9;
  for (int i = t; i < 512; i += 256) {
    int g = d0 + i;
    if (g < n) {
      offs[g] = b * CAP + offl[i];
      int dg = hist[i];
      deg[g] = dg;
      inv_deg[g] = 1.0f / fmaxf((float)dg, 1.0f);
    }
  }
  __syncthreads();
  for (int i = t; i < cnt; i += 256) {
    int e = ebuf[ebase + i];
    int p = atomicAdd(&offl[e & 511], 1);
    csr[ebase + p] = ((unsigned)e) >> 9;
  }
}

// ---------------- fused SAGE layer: fp8 gather-mean + bf16 MFMA combine ----------------
// Gather reads fp8 e5m2 rows (128B = 2 x 64B lines/edge, 16 lanes x 8B), f32
// accumulate, mean -> LDS bf16. Root path + MFMA stay bf16. Epilogue writes
// both bf16 (root/next-MFMA) and fp8 (next gather) copies.
template<bool EMIT_Z>
__global__ __launch_bounds__(256)
void sage_fused_kernel(const unsigned short* __restrict__ x, const unsigned char* __restrict__ xf8,
                       const int* __restrict__ csr,
                       const int* __restrict__ offs, const int* __restrict__ deg,
                       const float* __restrict__ inv_deg,
                       const unsigned short* __restrict__ Wp, const float* __restrict__ bias,
                       unsigned short* __restrict__ out, unsigned char* __restrict__ outf8,
                       const float* __restrict__ wl, const float* __restrict__ wr,
                       float* __restrict__ zl, float* __restrict__ zr, int n) {
  __shared__ int lcsr[ALCSR];
  __shared__ __align__(16) unsigned short lagg[16][136];
  __shared__ float zpart[2][4][16];
  const int t = threadIdx.x;
  const int node0 = blockIdx.x * 16;
  int last = node0 + 15; if (last >= n) last = n - 1;
  const int s_begin = offs[node0];
  const int total = offs[last] + deg[last] - s_begin;   // contiguous: 16 | NPB
  const bool useLds = (total <= ALCSR);
  if (useLds) {
    for (int k = t; k < total; k += 256) lcsr[k] = csr[s_begin + k];
  }
  __syncthreads();

  const int w = t >> 6, l = t & 63;
  {  // ---- gather phase: 4 nodes per wave, fp8 rows, 2-deep chains ----
    const int g = l >> 4, j = l & 15;
    const int node = node0 + w * 4 + g;
    if (node < n) {
      const unsigned char* xj = xf8 + 8 * j;
      const int lb = offs[node] - s_begin;
      const int d = deg[node];
      float2 a0[4] = {{0.f,0.f},{0.f,0.f},{0.f,0.f},{0.f,0.f}};
      float2 a1[4] = {{0.f,0.f},{0.f,0.f},{0.f,0.f},{0.f,0.f}};
      auto acc8 = [](float2* A, uint2 v) {
        A[0].x += e5m2hi2f((v.x << 8) & 0xff00u);
        A[0].y += e5m2hi2f(v.x & 0xff00u);
        A[1].x += e5m2hi2f((v.x >> 8) & 0xff00u);
        A[1].y += e5m2hi2f((v.x >> 16) & 0xff00u);
        A[2].x += e5m2hi2f((v.y << 8) & 0xff00u);
        A[2].y += e5m2hi2f(v.y & 0xff00u);
        A[3].x += e5m2hi2f((v.y >> 8) & 0xff00u);
        A[3].y += e5m2hi2f((v.y >> 16) & 0xff00u);
      };
      int i = 0;
      if (useLds) {
        for (; i + 3 < d; i += 4) {
          int e0 = lcsr[lb + i], e1 = lcsr[lb + i + 1];
          int e2 = lcsr[lb + i + 2], e3 = lcsr[lb + i + 3];
          uint2 v0 = *(const uint2*)(xj + (size_t)e0 * HD);
          uint2 v1 = *(const uint2*)(xj + (size_t)e1 * HD);
          uint2 v2 = *(const uint2*)(xj + (size_t)e2 * HD);
          uint2 v3 = *(const uint2*)(xj + (size_t)e3 * HD);
          acc8(a0, v0); acc8(a1, v1); acc8(a0, v2); acc8(a1, v3);
        }
        if (i + 1 < d) {
          int e0 = lcsr[lb + i], e1 = lcsr[lb + i + 1];
          uint2 v0 = *(const uint2*)(xj + (size_t)e0 * HD);
          uint2 v1 = *(const uint2*)(xj + (size_t)e1 * HD);
          acc8(a0, v0); acc8(a1, v1);
          i += 2;
        }
        if (i < d) {
          int e0 = lcsr[lb + i];
          acc8(a0, *(const uint2*)(xj + (size_t)e0 * HD));
        }
      } else {
        const int* gcsr = csr + s_begin + lb;
        for (; i + 3 < d; i += 4) {
          int e0 = gcsr[i], e1 = gcsr[i + 1], e2 = gcsr[i + 2], e3 = gcsr[i + 3];
          uint2 v0 = *(const uint2*)(xj + (size_t)e0 * HD);
          uint2 v1 = *(const uint2*)(xj + (size_t)e1 * HD);
          uint2 v2 = *(const uint2*)(xj + (size_t)e2 * HD);
          uint2 v3 = *(const uint2*)(xj + (size_t)e3 * HD);
          acc8(a0, v0); acc8(a1, v1); acc8(a0, v2); acc8(a1, v3);
        }
        if (i + 1 < d) {
          int e0 = gcsr[i], e1 = gcsr[i + 1];
          uint2 v0 = *(const uint2*)(xj + (size_t)e0 * HD);
          uint2 v1 = *(const uint2*)(xj + (size_t)e1 * HD);
          acc8(a0, v0); acc8(a1, v1);
          i += 2;
        }
        if (i < d) {
          int e0 = gcsr[i];
          acc8(a0, *(const uint2*)(xj + (size_t)e0 * HD));
        }
      }
      const float id = inv_deg[node];
      uint4 o;
      unsigned* op = (unsigned*)&o;
      #pragma unroll
      for (int k = 0; k < 4; k++) {
        float lo = (a0[k].x + a1[k].x) * id;
        float hi = (a0[k].y + a1[k].y) * id;
        op[k] = (unsigned)f2bf(lo) | ((unsigned)f2bf(hi) << 16);
      }
      *(uint4*)&lagg[w * 4 + g][j * 8] = o;
    } else {
      *(uint4*)&lagg[w * 4 + g][j * 8] = make_uint4(0, 0, 0, 0);
    }
  }
  __syncthreads();

  // ---- MFMA phase: wave w owns col-frags 2w, 2w+1 ----
  const int lr = l & 15, lg = l >> 4;
  int ra = node0 + lr; if (ra >= n) ra = n - 1;
  const unsigned short* wbase = Wp + (size_t)lr * 32 + (size_t)lg * 8;
  const unsigned short* rbase = x + (size_t)ra * HD + 8 * lg;

  f32x4 acc[2];
  #pragma unroll
  for (int c = 0; c < 2; c++) {
    float bv = bias[(2 * w + c) * 16 + lr];
    acc[c] = (f32x4){bv, bv, bv, bv};
  }
  #pragma unroll
  for (int ks = 0; ks < 4; ks++) {
    bf16x8 af = *(const bf16x8*)&lagg[lr][lg * 8 + ks * 32];
    #pragma unroll
    for (int c = 0; c < 2; c++) {
      int cb = 2 * w + c;
      bf16x8 bfv = *(const bf16x8*)(wbase + (size_t)(ks * 128 + cb * 16) * 32);
      acc[c] = __builtin_amdgcn_mfma_f32_16x16x32_bf16(af, bfv, acc[c], 0, 0, 0);
    }
  }
  #pragma unroll
  for (int ks = 0; ks < 4; ks++) {
    bf16x8 af = *(const bf16x8*)(rbase + ks * 32);
    #pragma unroll
    for (int c = 0; c < 2; c++) {
      int cb = 2 * w + c;
      bf16x8 bfv = *(const bf16x8*)(wbase + (size_t)((4 + ks) * 128 + cb * 16) * 32);
      acc[c] = __builtin_amdgcn_mfma_f32_16x16x32_bf16(af, bfv, acc[c], 0, 0, 0);
    }
  }

  if constexpr (!EMIT_Z) {
    #pragma unroll
    for (int c = 0; c < 2; c++) {
      int cb = 2 * w + c;
      #pragma unroll
      for (int r = 0; r < 4; r++) {
        int node = node0 + lg * 4 + r;
        if (node < n) {
          float val = lrelu(acc[c][r]);
          out[(size_t)node * HD + cb * 16 + lr] = f2bf(val);
          outf8[(size_t)node * HD + cb * 16 + lr] = f2e5m2(val);
        }
      }
    }
  } else {
    float vl[4] = {0.f, 0.f, 0.f, 0.f}, vr[4] = {0.f, 0.f, 0.f, 0.f};
    #pragma unroll
    for (int c = 0; c < 2; c++) {
      int cb = 2 * w + c;
      float wlv = wl[cb * 16 + lr];
      float wrv = wr[cb * 16 + lr];
      #pragma unroll
      for (int r = 0; r < 4; r++) {
        float x3 = lrelu(acc[c][r]);
        vl[r] += x3 * wlv;
        vr[r] += x3 * wrv;
      }
    }
    #pragma unroll
    for (int r = 0; r < 4; r++) {
      #pragma unroll
      for (int d = 1; d < 16; d <<= 1) {
        vl[r] += __shfl_xor(vl[r], d, 64);
        vr[r] += __shfl_xor(vr[r], d, 64);
      }
    }
    if (lr == 0) {
      #pragma unroll
      for (int r = 0; r < 4; r++) {
        zpart[0][w][lg * 4 + r] = vl[r];
        zpart[1][w][lg * 4 + r] = vr[r];
      }
    }
    __syncthreads();
    if (t < 16) {
      int node = node0 + t;
      if (node < n) {
        zl[node] = zpart[0][0][t] + zpart[0][1][t] + zpart[0][2][t] + zpart[0][3][t];
        zr[node] = zpart[1][0][t] + zpart[1][1][t] + zpart[1][2][t] + zpart[1][3][t];
      }
    }
  }
}

// ---------------- final: out = sigmoid(mean(zl) + zr + bl) ----------------
__global__ __launch_bounds__(256)
void zfinal_kernel(const float* __restrict__ zl, const float* __restrict__ zr,
                   const int* __restrict__ csr, const int* __restrict__ offs,
                   const int* __restrict__ deg, const float* __restrict__ inv_deg,
                   const float* __restrict__ bl, float* __restrict__ out, int n) {
  int i = blockIdx.x * 256 + threadIdx.x;
  if (i >= n) return;
  int s0 = offs[i], d = deg[i];
  float a = 0.f;
  #pragma unroll 4
  for (int e = 0; e < d; e++) a += zl[csr[s0 + e]];
  float s = a * inv_deg[i] + bl[0] + zr[i];
  out[i] = 1.0f / (1.0f + expf(-s));
}

extern "C" void kernel_launch(void* const* d_in, const int* in_sizes, int n_in,
                              void* d_out, int out_size, void* d_ws, size_t ws_size,
                              hipStream_t stream) {
  const float* x_gen  = (const float*)d_in[0];
  const float* x_load = (const float*)d_in[1];
  const float* x_or   = (const float*)d_in[2];
  const float* x_ex   = (const float*)d_in[3];
  const int*   edge   = (const int*)d_in[4];
  const int*   ptv    = (const int*)d_in[5];
  const float* Wg1  = (const float*)d_in[6],  *bg1  = (const float*)d_in[7];
  const float* Wg2  = (const float*)d_in[8],  *bg2  = (const float*)d_in[9];
  const float* Wld1 = (const float*)d_in[10], *bld1 = (const float*)d_in[11];
  const float* Wld2 = (const float*)d_in[12], *bld2 = (const float*)d_in[13];
  const float* Wor1 = (const float*)d_in[14], *bor1 = (const float*)d_in[15];
  const float* Wor2 = (const float*)d_in[16], *bor2 = (const float*)d_in[17];
  const float* Wex1 = (const float*)d_in[18], *bex1 = (const float*)d_in[19];
  const float* Wex2 = (const float*)d_in[20], *bex2 = (const float*)d_in[21];
  const float* Wl_h = (const float*)d_in[22], *bl_h = (const float*)d_in[23];
  const float* Wr_h = (const float*)d_in[24];
  const float* Wl_o = (const float*)d_in[25], *bl_o = (const float*)d_in[26];
  const float* Wr_o = (const float*)d_in[27];

  const int n_gen  = in_sizes[0] / 3;
  const int n_load = in_sizes[1] / 3;
  const int n_or   = in_sizes[2] / 6;
  const int n_ex   = in_sizes[3] / 6;
  const int nE     = in_sizes[4] / 2;
  const int N      = in_sizes[5];
  const int* esrc = edge;
  const int* edst = edge + nE;

  // padded segment geometry (each segment rounded to 64 rows)
  const int np0 = ((n_gen  + 63) / 64) * 64;
  const int np1 = ((n_load + 63) / 64) * 64;
  const int np2 = ((n_or   + 63) / 64) * 64;
  const int np3 = ((n_ex   + 63) / 64) * 64;
  const int NP  = np0 + np1 + np2 + np3;
  const int4 padCum    = make_int4(np0, np0 + np1, np0 + np1 + np2, NP);
  const int4 realStart = make_int4(0, n_gen, n_gen + n_load, n_gen + n_load + n_or);
  const int4 realCnt   = make_int4(n_gen, n_load, n_or, n_ex);

  const int NB = (N + NPB - 1) / NPB;   // buckets (<=256 for N<=131072)

  // ---- workspace layout ----
  size_t NPel = (size_t)NP * HD;
  size_t nel  = (size_t)N * HD;
  unsigned short* b0 = (unsigned short*)d_ws;  // h1 (padded)
  unsigned short* b1 = b0 + NPel;              // x current (bf16)
  unsigned short* b3 = b1 + nel;               // x next (bf16)
  int*  gcnt = (int*)(b3 + nel);               // 256 ints
  int*  ebuf = gcnt + 256;                     // NB*CAP packed edges
  int*  csr  = ebuf + (size_t)NB * CAP;
  int*  offs = csr + (size_t)NB * CAP;
  int*  deg  = offs + N;
  float* inv_deg = (float*)(deg + N);
  float* zl = inv_deg + N;
  float* zr = zl + N;
  int*  invp = (int*)(zr + N);
  uintptr_t wp_addr = ((uintptr_t)(invp + N) + 15) & ~(uintptr_t)15;
  unsigned short* Wp = (unsigned short*)wp_addr;   // 4*16384 + 3*32768 bf16
  uintptr_t f8_addr = ((uintptr_t)(Wp + 4 * 16384 + 3 * 32768) + 15) & ~(uintptr_t)15;
  unsigned char* f8a = (unsigned char*)f8_addr;    // N*HD bytes
  unsigned char* f8b = f8a + nel;                  // N*HD bytes

  // ---- weight repack + invptv + gcnt zero (one launch) ----
  wprep_all_kernel<<<640, 256, 0, stream>>>(Wg2, Wld2, Wor2, Wex2, Wl_h, Wr_h, Wp,
                                            ptv, invp, gcnt, N);

  // ---- embeddings ----
  embed1_kernel<<<NP / 2, 256, 0, stream>>>(x_gen, x_load, x_or, x_ex,
                                            Wg1, bg1, Wld1, bld1, Wor1, bor1, Wex1, bex1,
                                            b0, padCum, realCnt);
  mfma_embed2_kernel<<<NP / 64, 256, 0, stream>>>(b0, Wp, bg2, bld2, bor2, bex2,
                                                  invp, b1, padCum, realStart, realCnt);
  bf2f8_kernel<<<(N * 16 + 255) / 256, 256, 0, stream>>>(b1, f8a, N * 16);

  // ---- CSR build (bucketed, LDS-local atomics) ----
  bucket_scatter_kernel<<<(nE + SCHUNK - 1) / SCHUNK, 256, 0, stream>>>(esrc, edst, gcnt, ebuf, nE);
  bucket_build_kernel<<<NB, 256, 0, stream>>>(ebuf, gcnt, csr, offs, deg, inv_deg, N);

  // ---- hidden SAGE layers (fused fp8-gather + bf16 combine) ----
  const int fGrid = (N + 15) / 16;
  const unsigned short* WpC = Wp + 4 * 16384;
  unsigned short* xbf = b1;  unsigned char* xf8 = f8a;
  unsigned short* nbf = b3;  unsigned char* nf8 = f8b;
  for (int l = 0; l < 2; l++) {
    sage_fused_kernel<false><<<fGrid, 256, 0, stream>>>(
        xbf, xf8, csr, offs, deg, inv_deg, WpC + (size_t)l * 32768,
        bl_h + (size_t)l * HD, nbf, nf8, nullptr, nullptr, nullptr, nullptr, N);
    unsigned short* tb = xbf; xbf = nbf; nbf = tb;
    unsigned char*  tf = xf8; xf8 = nf8; nf8 = tf;
  }
  // layer 3 fused with output projection (zl = x3.Wl_o, zr = x3.Wr_o)
  sage_fused_kernel<true><<<fGrid, 256, 0, stream>>>(
      xbf, xf8, csr, offs, deg, inv_deg, WpC + 2 * 32768,
      bl_h + 2 * HD, nullptr, nullptr, Wl_o, Wr_o, zl, zr, N);

  // ---- final scalar aggregation + sigmoid ----
  zfinal_kernel<<<(N + 255) / 256, 256, 0, stream>>>(zl, zr, csr, offs, deg, inv_deg,
                                                     bl_o, (float*)d_out, N);
}

// Round 12
// 319.563 us; speedup vs baseline: 2.2455x; 1.0361x over previous
//
#include <hip/hip_runtime.h>
#include <hip/hip_bf16.h>
#include <hip/hip_fp16.h>
#include <math.h>

#define HD 128
#define NPB 512        // nodes per bucket
#define CAP 16384      // edge capacity per bucket (avg ~8163 -> 2x headroom)
#define SCHUNK 4096    // edges per scatter block
#define ALCSR 768      // staged csr entries per 16-node block (avg ~256)

typedef __attribute__((ext_vector_type(8))) short  bf16x8;
typedef __attribute__((ext_vector_type(4))) float  f32x4;
typedef __attribute__((ext_vector_type(2))) _Float16 h16x2;

__device__ __forceinline__ float lrelu(float v) { return v > 0.0f ? v : 0.1f * v; }

__device__ __forceinline__ unsigned short f2bf(float f) {
  union { float f; unsigned u; } c; c.f = f;
  unsigned u = c.u + 0x7fffu + ((c.u >> 16) & 1u);   // RNE
  return (unsigned short)(u >> 16);
}
__device__ __forceinline__ float bf2f(unsigned short u) {
  return __uint_as_float((unsigned)u << 16);
}
// fp8 e5m2 = top byte of fp16 (RNE twice: f32->f16->e5m2)
__device__ __forceinline__ unsigned char f2e5m2(float f) {
  unsigned short h = __half_as_ushort(__float2half(f));
  h = (unsigned short)(h + 0x7f + ((h >> 8) & 1));
  return (unsigned char)(h >> 8);
}

// ---------------- embedding layer 1 (all types, padded node ids) ----------------
__global__ __launch_bounds__(256)
void embed1_kernel(const float* __restrict__ xg, const float* __restrict__ xl,
                   const float* __restrict__ xo, const float* __restrict__ xe,
                   const float* __restrict__ Wg, const float* __restrict__ bg,
                   const float* __restrict__ Wl, const float* __restrict__ bl,
                   const float* __restrict__ Wo, const float* __restrict__ bo,
                   const float* __restrict__ We, const float* __restrict__ be,
                   unsigned short* __restrict__ h1, int4 padCum, int4 realCnt) {
  int p = blockIdx.x * 2 + (threadIdx.x >> 7);
  if (p >= padCum.w) return;
  int j = threadIdx.x & 127;
  int typ = (p < padCum.x) ? 0 : (p < padCum.y) ? 1 : (p < padCum.z) ? 2 : 3;
  int padStart = (typ == 0) ? 0 : (typ == 1) ? padCum.x : (typ == 2) ? padCum.y : padCum.z;
  int cnt = (typ == 0) ? realCnt.x : (typ == 1) ? realCnt.y : (typ == 2) ? realCnt.z : realCnt.w;
  int loc = p - padStart;
  if (loc >= cnt) return;
  const float *x, *W, *bb; int IN;
  if (typ == 0)      { x = xg; W = Wg; bb = bg; IN = 3; }
  else if (typ == 1) { x = xl; W = Wl; bb = bl; IN = 3; }
  else if (typ == 2) { x = xo; W = Wo; bb = bo; IN = 6; }
  else               { x = xe; W = We; bb = be; IN = 6; }
  float acc = bb[j];
  for (int k = 0; k < IN; k++) acc += x[(size_t)loc * IN + k] * W[k * HD + j];
  h1[(size_t)p * HD + j] = f2bf(lrelu(acc));
}

// ---------------- weight repack + invptv + gcnt zero ----------------
__global__ __launch_bounds__(256)
void wprep_all_kernel(const float* __restrict__ Wg2, const float* __restrict__ Wld2,
                      const float* __restrict__ Wor2, const float* __restrict__ Wex2,
                      const float* __restrict__ Wl_h, const float* __restrict__ Wr_h,
                      unsigned short* __restrict__ Wp,
                      const int* __restrict__ ptv, int* __restrict__ inv,
                      int* __restrict__ gcnt, int n) {
  int tid = blockIdx.x * 256 + threadIdx.x;      // 10 * 16384 total
  if (tid < 256) gcnt[tid] = 0;
  if (tid < n) inv[ptv[tid]] = tid;
  int m = tid >> 14;
  int i = tid & 16383;
  const float* src; unsigned short* dst;
  switch (m) {
    case 0: src = Wg2;  dst = Wp;             break;
    case 1: src = Wld2; dst = Wp + 16384;     break;
    case 2: src = Wor2; dst = Wp + 2 * 16384; break;
    case 3: src = Wex2; dst = Wp + 3 * 16384; break;
    default: {
      int mm = m - 4; int l = mm >> 1; int isR = mm & 1;
      src = (isR ? Wr_h : Wl_h) + (size_t)l * 16384;
      dst = Wp + 4 * 16384 + (size_t)l * 32768 + (isR ? 16384 : 0);
    }
  }
  int k = i >> 7, j = i & 127;
  int ks = k >> 5, g = (k >> 3) & 3, b = k & 7;
  dst[((ks * 128 + j) * 4 + g) * 8 + b] = f2bf(src[i]);
}

// ---------------- embedding layer 2 (MFMA), row-major out via invp ----------------
__global__ __launch_bounds__(256)
void mfma_embed2_kernel(const unsigned short* __restrict__ h1,
                        const unsigned short* __restrict__ Wp,
                        const float* __restrict__ b_g, const float* __restrict__ b_ld,
                        const float* __restrict__ b_or, const float* __restrict__ b_ex,
                        const int* __restrict__ inv, unsigned short* __restrict__ out,
                        int4 padCum, int4 realStart, int4 realCnt) {
  const int t = threadIdx.x, w = t >> 6, l = t & 63;
  const int lr = l & 15, lg = l >> 4;
  const int prow0 = blockIdx.x * 64 + w * 16;
  int typ = (prow0 < padCum.x) ? 0 : (prow0 < padCum.y) ? 1 : (prow0 < padCum.z) ? 2 : 3;
  int padStart = (typ == 0) ? 0 : (typ == 1) ? padCum.x : (typ == 2) ? padCum.y : padCum.z;
  int rStart = (typ == 0) ? realStart.x : (typ == 1) ? realStart.y : (typ == 2) ? realStart.z : realStart.w;
  int cnt = (typ == 0) ? realCnt.x : (typ == 1) ? realCnt.y : (typ == 2) ? realCnt.z : realCnt.w;
  const float* bias = (typ == 0) ? b_g : (typ == 1) ? b_ld : (typ == 2) ? b_or : b_ex;

  int raLoc = prow0 + lr - padStart; if (raLoc >= cnt) raLoc = cnt - 1;
  const unsigned short* abase = h1 + (size_t)(padStart + raLoc) * HD + 8 * lg;
  const unsigned short* wbase = Wp + (size_t)typ * 16384 + lr * 32 + lg * 8;

  f32x4 acc[8];
  #pragma unroll
  for (int cb = 0; cb < 8; cb++) {
    float bv = bias[cb * 16 + lr];
    acc[cb] = (f32x4){bv, bv, bv, bv};
  }
  #pragma unroll
  for (int ks = 0; ks < 4; ks++) {
    bf16x8 af = *(const bf16x8*)(abase + ks * 32);
    #pragma unroll
    for (int cb = 0; cb < 8; cb++) {
      bf16x8 bfv = *(const bf16x8*)(wbase + (size_t)(ks * 128 + cb * 16) * 32);
      acc[cb] = __builtin_amdgcn_mfma_f32_16x16x32_bf16(af, bfv, acc[cb], 0, 0, 0);
    }
  }
  int tgt[4];
  #pragma unroll
  for (int r = 0; r < 4; r++) {
    int locRow = prow0 + lg * 4 + r - padStart;
    tgt[r] = (locRow < cnt) ? inv[rStart + locRow] : -1;
  }
  #pragma unroll
  for (int cb = 0; cb < 8; cb++) {
    #pragma unroll
    for (int r = 0; r < 4; r++) {
      if (tgt[r] >= 0)
        out[(size_t)tgt[r] * HD + cb * 16 + lr] = f2bf(lrelu(acc[cb][r]));
    }
  }
}

// ---------------- bf16 row-major -> fp8 e5m2 copy (one-time, coalesced) ----------------
__global__ __launch_bounds__(256)
void bf2f8_kernel(const unsigned short* __restrict__ in, unsigned char* __restrict__ out, int n8) {
  int idx = blockIdx.x * 256 + threadIdx.x;   // one thread per 8 elements
  if (idx >= n8) return;
  uint4 v = *(const uint4*)(in + (size_t)idx * 8);
  unsigned char b0 = f2e5m2(__uint_as_float(v.x << 16));
  unsigned char b1 = f2e5m2(__uint_as_float(v.x & 0xffff0000u));
  unsigned char b2 = f2e5m2(__uint_as_float(v.y << 16));
  unsigned char b3 = f2e5m2(__uint_as_float(v.y & 0xffff0000u));
  unsigned char b4 = f2e5m2(__uint_as_float(v.z << 16));
  unsigned char b5 = f2e5m2(__uint_as_float(v.z & 0xffff0000u));
  unsigned char b6 = f2e5m2(__uint_as_float(v.w << 16));
  unsigned char b7 = f2e5m2(__uint_as_float(v.w & 0xffff0000u));
  uint2 o;
  o.x = (unsigned)b0 | ((unsigned)b1 << 8) | ((unsigned)b2 << 16) | ((unsigned)b3 << 24);
  o.y = (unsigned)b4 | ((unsigned)b5 << 8) | ((unsigned)b6 << 16) | ((unsigned)b7 << 24);
  *(uint2*)(out + (size_t)idx * 8) = o;
}

// ---------------- CSR build phase 1: bucket scatter (packed int) ----------------
__global__ __launch_bounds__(256)
void bucket_scatter_kernel(const int* __restrict__ esrc, const int* __restrict__ edst,
                           int* __restrict__ gcnt, int* __restrict__ ebuf, int nE) {
  __shared__ int cnt[256];
  __shared__ int cur[256];
  const int t = threadIdx.x;
  const int c0 = blockIdx.x * SCHUNK;
  int s_arr[16], d_arr[16];
  cnt[t] = 0;
  __syncthreads();
  #pragma unroll
  for (int k = 0; k < 16; k++) {
    int idx = c0 + k * 256 + t;
    if (idx < nE) {
      s_arr[k] = esrc[idx];
      int d = edst[idx];
      d_arr[k] = d;
      atomicAdd(&cnt[d >> 9], 1);
    } else d_arr[k] = -1;
  }
  __syncthreads();
  if (cnt[t] > 0) cur[t] = atomicAdd(&gcnt[t], cnt[t]);
  __syncthreads();
  #pragma unroll
  for (int k = 0; k < 16; k++) {
    if (d_arr[k] >= 0) {
      int b = d_arr[k] >> 9;
      int p = atomicAdd(&cur[b], 1);
      ebuf[(size_t)b * CAP + p] = (s_arr[k] << 9) | (d_arr[k] & 511);
    }
  }
}

__device__ __forceinline__ int wave_incl_scan(int v) {
  int lane = threadIdx.x & 63;
  #pragma unroll
  for (int d = 1; d < 64; d <<= 1) {
    int tv = __shfl_up(v, d, 64);
    if (lane >= d) v += tv;
  }
  return v;
}

// ---------------- CSR build phase 2: per-bucket local build ----------------
__global__ __launch_bounds__(256)
void bucket_build_kernel(const int* __restrict__ ebuf, const int* __restrict__ gcnt,
                         int* __restrict__ csr, int* __restrict__ offs,
                         int* __restrict__ deg, float* __restrict__ inv_deg, int n) {
  __shared__ int hist[512];
  __shared__ int offl[512];
  __shared__ int wsum[4];
  const int b = blockIdx.x, t = threadIdx.x;
  const int cnt = gcnt[b];
  const size_t ebase = (size_t)b * CAP;
  hist[t] = 0; hist[t + 256] = 0;
  __syncthreads();
  for (int i = t; i < cnt; i += 256) {
    int e = ebuf[ebase + i];
    atomicAdd(&hist[e & 511], 1);
  }
  __syncthreads();
  int a0 = hist[2 * t], a1 = hist[2 * t + 1];
  int s = a0 + a1;
  int incl = wave_incl_scan(s);
  int wid = t >> 6;
  if ((t & 63) == 63) wsum[wid] = incl;
  __syncthreads();
  int wbase = 0;
  for (int w_ = 0; w_ < wid; w_++) wbase += wsum[w_];
  int excl = wbase + incl - s;
  offl[2 * t] = excl;
  offl[2 * t + 1] = excl + a0;
  __syncthreads();
  const int d0 = b << 9;
  for (int i = t; i < 512; i += 256) {
    int g = d0 + i;
    if (g < n) {
      offs[g] = b * CAP + offl[i];
      int dg = hist[i];
      deg[g] = dg;
      inv_deg[g] = 1.0f / fmaxf((float)dg, 1.0f);
    }
  }
  __syncthreads();
  for (int i = t; i < cnt; i += 256) {
    int e = ebuf[ebase + i];
    int p = atomicAdd(&offl[e & 511], 1);
    csr[ebase + p] = ((unsigned)e) >> 9;
  }
}

// ---------------- fused SAGE layer: fp8 gather (v_perm + pk_add_f16) + bf16 MFMA ----------------
// e5m2 byte<<8 IS fp16: v_perm builds half2 from 2 bytes (1 op), v_pk_add_f16
// accumulates 2 elems (1 op) -> 8 VALU per 8 elems vs 24 scalar. f32 only at mean.
template<bool EMIT_Z>
__global__ __launch_bounds__(256)
void sage_fused_kernel(const unsigned short* __restrict__ x, const unsigned char* __restrict__ xf8,
                       const int* __restrict__ csr,
                       const int* __restrict__ offs, const int* __restrict__ deg,
                       const float* __restrict__ inv_deg,
                       const unsigned short* __restrict__ Wp, const float* __restrict__ bias,
                       unsigned short* __restrict__ out, unsigned char* __restrict__ outf8,
                       const float* __restrict__ wl, const float* __restrict__ wr,
                       float* __restrict__ zl, float* __restrict__ zr, int n) {
  __shared__ int lcsr[ALCSR];
  __shared__ __align__(16) unsigned short lagg[16][136];
  __shared__ float zpart[2][4][16];
  const int t = threadIdx.x;
  const int node0 = blockIdx.x * 16;
  int last = node0 + 15; if (last >= n) last = n - 1;
  const int s_begin = offs[node0];
  const int total = offs[last] + deg[last] - s_begin;   // contiguous: 16 | NPB
  const bool useLds = (total <= ALCSR);
  if (useLds) {
    for (int k = t; k < total; k += 256) lcsr[k] = csr[s_begin + k];
  }
  __syncthreads();

  const int w = t >> 6, l = t & 63;
  {  // ---- gather phase: 4 nodes per wave, fp8 rows, packed-fp16 accumulate ----
    const int g = l >> 4, j = l & 15;
    const int node = node0 + w * 4 + g;
    if (node < n) {
      const unsigned char* xj = xf8 + 8 * j;
      const int lb = offs[node] - s_begin;
      const int d = deg[node];
      h16x2 a0[4], a1[4];
      #pragma unroll
      for (int k = 0; k < 4; k++) {
        a0[k] = (h16x2){(_Float16)0, (_Float16)0};
        a1[k] = (h16x2){(_Float16)0, (_Float16)0};
      }
      // result byte layout: [b_odd, 0, b_even, 0] -> half2 (b_even<<8, b_odd<<8)
      auto acc8 = [](h16x2* A, uint2 v) {
        unsigned p0 = __builtin_amdgcn_perm(0u, v.x, 0x01040004u);  // b0,b1
        unsigned p1 = __builtin_amdgcn_perm(0u, v.x, 0x03040204u);  // b2,b3
        unsigned p2 = __builtin_amdgcn_perm(0u, v.y, 0x01040004u);  // b4,b5
        unsigned p3 = __builtin_amdgcn_perm(0u, v.y, 0x03040204u);  // b6,b7
        A[0] += __builtin_bit_cast(h16x2, p0);
        A[1] += __builtin_bit_cast(h16x2, p1);
        A[2] += __builtin_bit_cast(h16x2, p2);
        A[3] += __builtin_bit_cast(h16x2, p3);
      };
      int i = 0;
      if (useLds) {
        for (; i + 3 < d; i += 4) {
          int e0 = lcsr[lb + i], e1 = lcsr[lb + i + 1];
          int e2 = lcsr[lb + i + 2], e3 = lcsr[lb + i + 3];
          uint2 v0 = *(const uint2*)(xj + (size_t)e0 * HD);
          uint2 v1 = *(const uint2*)(xj + (size_t)e1 * HD);
          uint2 v2 = *(const uint2*)(xj + (size_t)e2 * HD);
          uint2 v3 = *(const uint2*)(xj + (size_t)e3 * HD);
          acc8(a0, v0); acc8(a1, v1); acc8(a0, v2); acc8(a1, v3);
        }
        if (i + 1 < d) {
          int e0 = lcsr[lb + i], e1 = lcsr[lb + i + 1];
          uint2 v0 = *(const uint2*)(xj + (size_t)e0 * HD);
          uint2 v1 = *(const uint2*)(xj + (size_t)e1 * HD);
          acc8(a0, v0); acc8(a1, v1);
          i += 2;
        }
        if (i < d) {
          int e0 = lcsr[lb + i];
          acc8(a0, *(const uint2*)(xj + (size_t)e0 * HD));
        }
      } else {
        const int* gcsr = csr + s_begin + lb;
        for (; i + 3 < d; i += 4) {
          int e0 = gcsr[i], e1 = gcsr[i + 1], e2 = gcsr[i + 2], e3 = gcsr[i + 3];
          uint2 v0 = *(const uint2*)(xj + (size_t)e0 * HD);
          uint2 v1 = *(const uint2*)(xj + (size_t)e1 * HD);
          uint2 v2 = *(const uint2*)(xj + (size_t)e2 * HD);
          uint2 v3 = *(const uint2*)(xj + (size_t)e3 * HD);
          acc8(a0, v0); acc8(a1, v1); acc8(a0, v2); acc8(a1, v3);
        }
        if (i + 1 < d) {
          int e0 = gcsr[i], e1 = gcsr[i + 1];
          uint2 v0 = *(const uint2*)(xj + (size_t)e0 * HD);
          uint2 v1 = *(const uint2*)(xj + (size_t)e1 * HD);
          acc8(a0, v0); acc8(a1, v1);
          i += 2;
        }
        if (i < d) {
          int e0 = gcsr[i];
          acc8(a0, *(const uint2*)(xj + (size_t)e0 * HD));
        }
      }
      const float id = inv_deg[node];
      uint4 o;
      unsigned* op = (unsigned*)&o;
      #pragma unroll
      for (int k = 0; k < 4; k++) {
        float lo = ((float)a0[k][0] + (float)a1[k][0]) * id;
        float hi = ((float)a0[k][1] + (float)a1[k][1]) * id;
        op[k] = (unsigned)f2bf(lo) | ((unsigned)f2bf(hi) << 16);
      }
      *(uint4*)&lagg[w * 4 + g][j * 8] = o;
    } else {
      *(uint4*)&lagg[w * 4 + g][j * 8] = make_uint4(0, 0, 0, 0);
    }
  }
  __syncthreads();

  // ---- MFMA phase: wave w owns col-frags 2w, 2w+1 ----
  const int lr = l & 15, lg = l >> 4;
  int ra = node0 + lr; if (ra >= n) ra = n - 1;
  const unsigned short* wbase = Wp + (size_t)lr * 32 + (size_t)lg * 8;
  const unsigned short* rbase = x + (size_t)ra * HD + 8 * lg;

  f32x4 acc[2];
  #pragma unroll
  for (int c = 0; c < 2; c++) {
    float bv = bias[(2 * w + c) * 16 + lr];
    acc[c] = (f32x4){bv, bv, bv, bv};
  }
  #pragma unroll
  for (int ks = 0; ks < 4; ks++) {
    bf16x8 af = *(const bf16x8*)&lagg[lr][lg * 8 + ks * 32];
    #pragma unroll
    for (int c = 0; c < 2; c++) {
      int cb = 2 * w + c;
      bf16x8 bfv = *(const bf16x8*)(wbase + (size_t)(ks * 128 + cb * 16) * 32);
      acc[c] = __builtin_amdgcn_mfma_f32_16x16x32_bf16(af, bfv, acc[c], 0, 0, 0);
    }
  }
  #pragma unroll
  for (int ks = 0; ks < 4; ks++) {
    bf16x8 af = *(const bf16x8*)(rbase + ks * 32);
    #pragma unroll
    for (int c = 0; c < 2; c++) {
      int cb = 2 * w + c;
      bf16x8 bfv = *(const bf16x8*)(wbase + (size_t)((4 + ks) * 128 + cb * 16) * 32);
      acc[c] = __builtin_amdgcn_mfma_f32_16x16x32_bf16(af, bfv, acc[c], 0, 0, 0);
    }
  }

  if constexpr (!EMIT_Z) {
    #pragma unroll
    for (int c = 0; c < 2; c++) {
      int cb = 2 * w + c;
      #pragma unroll
      for (int r = 0; r < 4; r++) {
        int node = node0 + lg * 4 + r;
        if (node < n) {
          float val = lrelu(acc[c][r]);
          out[(size_t)node * HD + cb * 16 + lr] = f2bf(val);
          outf8[(size_t)node * HD + cb * 16 + lr] = f2e5m2(val);
        }
      }
    }
  } else {
    float vl[4] = {0.f, 0.f, 0.f, 0.f}, vr[4] = {0.f, 0.f, 0.f, 0.f};
    #pragma unroll
    for (int c = 0; c < 2; c++) {
      int cb = 2 * w + c;
      float wlv = wl[cb * 16 + lr];
      float wrv = wr[cb * 16 + lr];
      #pragma unroll
      for (int r = 0; r < 4; r++) {
        float x3 = lrelu(acc[c][r]);
        vl[r] += x3 * wlv;
        vr[r] += x3 * wrv;
      }
    }
    #pragma unroll
    for (int r = 0; r < 4; r++) {
      #pragma unroll
      for (int d = 1; d < 16; d <<= 1) {
        vl[r] += __shfl_xor(vl[r], d, 64);
        vr[r] += __shfl_xor(vr[r], d, 64);
      }
    }
    if (lr == 0) {
      #pragma unroll
      for (int r = 0; r < 4; r++) {
        zpart[0][w][lg * 4 + r] = vl[r];
        zpart[1][w][lg * 4 + r] = vr[r];
      }
    }
    __syncthreads();
    if (t < 16) {
      int node = node0 + t;
      if (node < n) {
        zl[node] = zpart[0][0][t] + zpart[0][1][t] + zpart[0][2][t] + zpart[0][3][t];
        zr[node] = zpart[1][0][t] + zpart[1][1][t] + zpart[1][2][t] + zpart[1][3][t];
      }
    }
  }
}

// ---------------- final: out = sigmoid(mean(zl) + zr + bl) ----------------
__global__ __launch_bounds__(256)
void zfinal_kernel(const float* __restrict__ zl, const float* __restrict__ zr,
                   const int* __restrict__ csr, const int* __restrict__ offs,
                   const int* __restrict__ deg, const float* __restrict__ inv_deg,
                   const float* __restrict__ bl, float* __restrict__ out, int n) {
  int i = blockIdx.x * 256 + threadIdx.x;
  if (i >= n) return;
  int s0 = offs[i], d = deg[i];
  float a = 0.f;
  #pragma unroll 4
  for (int e = 0; e < d; e++) a += zl[csr[s0 + e]];
  float s = a * inv_deg[i] + bl[0] + zr[i];
  out[i] = 1.0f / (1.0f + expf(-s));
}

extern "C" void kernel_launch(void* const* d_in, const int* in_sizes, int n_in,
                              void* d_out, int out_size, void* d_ws, size_t ws_size,
                              hipStream_t stream) {
  const float* x_gen  = (const float*)d_in[0];
  const float* x_load = (const float*)d_in[1];
  const float* x_or   = (const float*)d_in[2];
  const float* x_ex   = (const float*)d_in[3];
  const int*   edge   = (const int*)d_in[4];
  const int*   ptv    = (const int*)d_in[5];
  const float* Wg1  = (const float*)d_in[6],  *bg1  = (const float*)d_in[7];
  const float* Wg2  = (const float*)d_in[8],  *bg2  = (const float*)d_in[9];
  const float* Wld1 = (const float*)d_in[10], *bld1 = (const float*)d_in[11];
  const float* Wld2 = (const float*)d_in[12], *bld2 = (const float*)d_in[13];
  const float* Wor1 = (const float*)d_in[14], *bor1 = (const float*)d_in[15];
  const float* Wor2 = (const float*)d_in[16], *bor2 = (const float*)d_in[17];
  const float* Wex1 = (const float*)d_in[18], *bex1 = (const float*)d_in[19];
  const float* Wex2 = (const float*)d_in[20], *bex2 = (const float*)d_in[21];
  const float* Wl_h = (const float*)d_in[22], *bl_h = (const float*)d_in[23];
  const float* Wr_h = (const float*)d_in[24];
  const float* Wl_o = (const float*)d_in[25], *bl_o = (const float*)d_in[26];
  const float* Wr_o = (const float*)d_in[27];

  const int n_gen  = in_sizes[0] / 3;
  const int n_load = in_sizes[1] / 3;
  const int n_or   = in_sizes[2] / 6;
  const int n_ex   = in_sizes[3] / 6;
  const int nE     = in_sizes[4] / 2;
  const int N      = in_sizes[5];
  const int* esrc = edge;
  const int* edst = edge + nE;

  // padded segment geometry (each segment rounded to 64 rows)
  const int np0 = ((n_gen  + 63) / 64) * 64;
  const int np1 = ((n_load + 63) / 64) * 64;
  const int np2 = ((n_or   + 63) / 64) * 64;
  const int np3 = ((n_ex   + 63) / 64) * 64;
  const int NP  = np0 + np1 + np2 + np3;
  const int4 padCum    = make_int4(np0, np0 + np1, np0 + np1 + np2, NP);
  const int4 realStart = make_int4(0, n_gen, n_gen + n_load, n_gen + n_load + n_or);
  const int4 realCnt   = make_int4(n_gen, n_load, n_or, n_ex);

  const int NB = (N + NPB - 1) / NPB;   // buckets (<=256 for N<=131072)

  // ---- workspace layout ----
  size_t NPel = (size_t)NP * HD;
  size_t nel  = (size_t)N * HD;
  unsigned short* b0 = (unsigned short*)d_ws;  // h1 (padded)
  unsigned short* b1 = b0 + NPel;              // x current (bf16)
  unsigned short* b3 = b1 + nel;               // x next (bf16)
  int*  gcnt = (int*)(b3 + nel);               // 256 ints
  int*  ebuf = gcnt + 256;                     // NB*CAP packed edges
  int*  csr  = ebuf + (size_t)NB * CAP;
  int*  offs = csr + (size_t)NB * CAP;
  int*  deg  = offs + N;
  float* inv_deg = (float*)(deg + N);
  float* zl = inv_deg + N;
  float* zr = zl + N;
  int*  invp = (int*)(zr + N);
  uintptr_t wp_addr = ((uintptr_t)(invp + N) + 15) & ~(uintptr_t)15;
  unsigned short* Wp = (unsigned short*)wp_addr;   // 4*16384 + 3*32768 bf16
  uintptr_t f8_addr = ((uintptr_t)(Wp + 4 * 16384 + 3 * 32768) + 15) & ~(uintptr_t)15;
  unsigned char* f8a = (unsigned char*)f8_addr;    // N*HD bytes
  unsigned char* f8b = f8a + nel;                  // N*HD bytes

  // ---- weight repack + invptv + gcnt zero (one launch) ----
  wprep_all_kernel<<<640, 256, 0, stream>>>(Wg2, Wld2, Wor2, Wex2, Wl_h, Wr_h, Wp,
                                            ptv, invp, gcnt, N);

  // ---- embeddings ----
  embed1_kernel<<<NP / 2, 256, 0, stream>>>(x_gen, x_load, x_or, x_ex,
                                            Wg1, bg1, Wld1, bld1, Wor1, bor1, Wex1, bex1,
                                            b0, padCum, realCnt);
  mfma_embed2_kernel<<<NP / 64, 256, 0, stream>>>(b0, Wp, bg2, bld2, bor2, bex2,
                                                  invp, b1, padCum, realStart, realCnt);
  bf2f8_kernel<<<(N * 16 + 255) / 256, 256, 0, stream>>>(b1, f8a, N * 16);

  // ---- CSR build (bucketed, LDS-local atomics) ----
  bucket_scatter_kernel<<<(nE + SCHUNK - 1) / SCHUNK, 256, 0, stream>>>(esrc, edst, gcnt, ebuf, nE);
  bucket_build_kernel<<<NB, 256, 0, stream>>>(ebuf, gcnt, csr, offs, deg, inv_deg, N);

  // ---- hidden SAGE layers (fused fp8-gather + bf16 combine) ----
  const int fGrid = (N + 15) / 16;
  const unsigned short* WpC = Wp + 4 * 16384;
  unsigned short* xbf = b1;  unsigned char* xf8 = f8a;
  unsigned short* nbf = b3;  unsigned char* nf8 = f8b;
  for (int l = 0; l < 2; l++) {
    sage_fused_kernel<false><<<fGrid, 256, 0, stream>>>(
        xbf, xf8, csr, offs, deg, inv_deg, WpC + (size_t)l * 32768,
        bl_h + (size_t)l * HD, nbf, nf8, nullptr, nullptr, nullptr, nullptr, N);
    unsigned short* tb = xbf; xbf = nbf; nbf = tb;
    unsigned char*  tf = xf8; xf8 = nf8; nf8 = tf;
  }
  // layer 3 fused with output projection (zl = x3.Wl_o, zr = x3.Wr_o)
  sage_fused_kernel<true><<<fGrid, 256, 0, stream>>>(
      xbf, xf8, csr, offs, deg, inv_deg, WpC + 2 * 32768,
      bl_h + 2 * HD, nullptr, nullptr, Wl_o, Wr_o, zl, zr, N);

  // ---- final scalar aggregation + sigmoid ----
  zfinal_kernel<<<(N + 255) / 256, 256, 0, stream>>>(zl, zr, csr, offs, deg, inv_deg,
                                                     bl_o, (float*)d_out, N);
}

// Round 13
// 315.080 us; speedup vs baseline: 2.2775x; 1.0142x over previous
//
#include <hip/hip_runtime.h>
#include <hip/hip_bf16.h>
#include <hip/hip_fp16.h>
#include <math.h>

#define HD 128
#define NPB 512        // nodes per bucket
#define CAP 16384      // edge capacity per bucket (avg ~8192 -> 2x headroom)
#define SCHUNK 4096    // edges per scatter block
#define ALCSR 768      // staged csr entries per 16-node block (avg ~256)
#define LCAP 9216      // LDS csr buffer in bucket_build (avg cnt ~8192, sigma ~90)

typedef __attribute__((ext_vector_type(8))) short  bf16x8;
typedef __attribute__((ext_vector_type(4))) float  f32x4;
typedef __attribute__((ext_vector_type(2))) _Float16 h16x2;

__device__ __forceinline__ float lrelu(float v) { return v > 0.0f ? v : 0.1f * v; }

__device__ __forceinline__ unsigned short f2bf(float f) {
  union { float f; unsigned u; } c; c.f = f;
  unsigned u = c.u + 0x7fffu + ((c.u >> 16) & 1u);   // RNE
  return (unsigned short)(u >> 16);
}
__device__ __forceinline__ float bf2f(unsigned short u) {
  return __uint_as_float((unsigned)u << 16);
}
// fp8 e5m2 = top byte of fp16 (RNE twice: f32->f16->e5m2)
__device__ __forceinline__ unsigned char f2e5m2(float f) {
  unsigned short h = __half_as_ushort(__float2half(f));
  h = (unsigned short)(h + 0x7f + ((h >> 8) & 1));
  return (unsigned char)(h >> 8);
}

// ---------------- embedding layer 1 (all types, padded node ids) ----------------
__global__ __launch_bounds__(256)
void embed1_kernel(const float* __restrict__ xg, const float* __restrict__ xl,
                   const float* __restrict__ xo, const float* __restrict__ xe,
                   const float* __restrict__ Wg, const float* __restrict__ bg,
                   const float* __restrict__ Wl, const float* __restrict__ bl,
                   const float* __restrict__ Wo, const float* __restrict__ bo,
                   const float* __restrict__ We, const float* __restrict__ be,
                   unsigned short* __restrict__ h1, int4 padCum, int4 realCnt) {
  int p = blockIdx.x * 2 + (threadIdx.x >> 7);
  if (p >= padCum.w) return;
  int j = threadIdx.x & 127;
  int typ = (p < padCum.x) ? 0 : (p < padCum.y) ? 1 : (p < padCum.z) ? 2 : 3;
  int padStart = (typ == 0) ? 0 : (typ == 1) ? padCum.x : (typ == 2) ? padCum.y : padCum.z;
  int cnt = (typ == 0) ? realCnt.x : (typ == 1) ? realCnt.y : (typ == 2) ? realCnt.z : realCnt.w;
  int loc = p - padStart;
  if (loc >= cnt) return;
  const float *x, *W, *bb; int IN;
  if (typ == 0)      { x = xg; W = Wg; bb = bg; IN = 3; }
  else if (typ == 1) { x = xl; W = Wl; bb = bl; IN = 3; }
  else if (typ == 2) { x = xo; W = Wo; bb = bo; IN = 6; }
  else               { x = xe; W = We; bb = be; IN = 6; }
  float acc = bb[j];
  for (int k = 0; k < IN; k++) acc += x[(size_t)loc * IN + k] * W[k * HD + j];
  h1[(size_t)p * HD + j] = f2bf(lrelu(acc));
}

// ---------------- weight repack + invptv + gcnt zero ----------------
__global__ __launch_bounds__(256)
void wprep_all_kernel(const float* __restrict__ Wg2, const float* __restrict__ Wld2,
                      const float* __restrict__ Wor2, const float* __restrict__ Wex2,
                      const float* __restrict__ Wl_h, const float* __restrict__ Wr_h,
                      unsigned short* __restrict__ Wp,
                      const int* __restrict__ ptv, int* __restrict__ inv,
                      int* __restrict__ gcnt, int n) {
  int tid = blockIdx.x * 256 + threadIdx.x;      // 10 * 16384 total
  if (tid < 256) gcnt[tid] = 0;
  if (tid < n) inv[ptv[tid]] = tid;
  int m = tid >> 14;
  int i = tid & 16383;
  const float* src; unsigned short* dst;
  switch (m) {
    case 0: src = Wg2;  dst = Wp;             break;
    case 1: src = Wld2; dst = Wp + 16384;     break;
    case 2: src = Wor2; dst = Wp + 2 * 16384; break;
    case 3: src = Wex2; dst = Wp + 3 * 16384; break;
    default: {
      int mm = m - 4; int l = mm >> 1; int isR = mm & 1;
      src = (isR ? Wr_h : Wl_h) + (size_t)l * 16384;
      dst = Wp + 4 * 16384 + (size_t)l * 32768 + (isR ? 16384 : 0);
    }
  }
  int k = i >> 7, j = i & 127;
  int ks = k >> 5, g = (k >> 3) & 3, b = k & 7;
  dst[((ks * 128 + j) * 4 + g) * 8 + b] = f2bf(src[i]);
}

// ---------------- embedding layer 2 (MFMA), row-major bf16 + fp8 out via invp ----------------
__global__ __launch_bounds__(256)
void mfma_embed2_kernel(const unsigned short* __restrict__ h1,
                        const unsigned short* __restrict__ Wp,
                        const float* __restrict__ b_g, const float* __restrict__ b_ld,
                        const float* __restrict__ b_or, const float* __restrict__ b_ex,
                        const int* __restrict__ inv, unsigned short* __restrict__ out,
                        unsigned char* __restrict__ outf8,
                        int4 padCum, int4 realStart, int4 realCnt) {
  const int t = threadIdx.x, w = t >> 6, l = t & 63;
  const int lr = l & 15, lg = l >> 4;
  const int prow0 = blockIdx.x * 64 + w * 16;
  int typ = (prow0 < padCum.x) ? 0 : (prow0 < padCum.y) ? 1 : (prow0 < padCum.z) ? 2 : 3;
  int padStart = (typ == 0) ? 0 : (typ == 1) ? padCum.x : (typ == 2) ? padCum.y : padCum.z;
  int rStart = (typ == 0) ? realStart.x : (typ == 1) ? realStart.y : (typ == 2) ? realStart.z : realStart.w;
  int cnt = (typ == 0) ? realCnt.x : (typ == 1) ? realCnt.y : (typ == 2) ? realCnt.z : realCnt.w;
  const float* bias = (typ == 0) ? b_g : (typ == 1) ? b_ld : (typ == 2) ? b_or : b_ex;

  int raLoc = prow0 + lr - padStart; if (raLoc >= cnt) raLoc = cnt - 1;
  const unsigned short* abase = h1 + (size_t)(padStart + raLoc) * HD + 8 * lg;
  const unsigned short* wbase = Wp + (size_t)typ * 16384 + lr * 32 + lg * 8;

  f32x4 acc[8];
  #pragma unroll
  for (int cb = 0; cb < 8; cb++) {
    float bv = bias[cb * 16 + lr];
    acc[cb] = (f32x4){bv, bv, bv, bv};
  }
  #pragma unroll
  for (int ks = 0; ks < 4; ks++) {
    bf16x8 af = *(const bf16x8*)(abase + ks * 32);
    #pragma unroll
    for (int cb = 0; cb < 8; cb++) {
      bf16x8 bfv = *(const bf16x8*)(wbase + (size_t)(ks * 128 + cb * 16) * 32);
      acc[cb] = __builtin_amdgcn_mfma_f32_16x16x32_bf16(af, bfv, acc[cb], 0, 0, 0);
    }
  }
  int tgt[4];
  #pragma unroll
  for (int r = 0; r < 4; r++) {
    int locRow = prow0 + lg * 4 + r - padStart;
    tgt[r] = (locRow < cnt) ? inv[rStart + locRow] : -1;
  }
  #pragma unroll
  for (int cb = 0; cb < 8; cb++) {
    #pragma unroll
    for (int r = 0; r < 4; r++) {
      if (tgt[r] >= 0) {
        float val = lrelu(acc[cb][r]);
        out[(size_t)tgt[r] * HD + cb * 16 + lr] = f2bf(val);
        outf8[(size_t)tgt[r] * HD + cb * 16 + lr] = f2e5m2(val);
      }
    }
  }
}

__device__ __forceinline__ int wave_incl_scan(int v) {
  int lane = threadIdx.x & 63;
  #pragma unroll
  for (int d = 1; d < 64; d <<= 1) {
    int tv = __shfl_up(v, d, 64);
    if (lane >= d) v += tv;
  }
  return v;
}

// ---------------- CSR build phase 1: bucket scatter (LDS-sorted, coalesced out) ----------------
__global__ __launch_bounds__(256)
void bucket_scatter_kernel(const int* __restrict__ esrc, const int* __restrict__ edst,
                           int* __restrict__ gcnt, int* __restrict__ ebuf, int nE) {
  __shared__ int cnt[256];
  __shared__ int loff[257];
  __shared__ int gbase[256];
  __shared__ int cur[256];
  __shared__ int wsum[4];
  __shared__ int sbuf[SCHUNK];   // 16KB
  const int t = threadIdx.x;
  const int c0 = blockIdx.x * SCHUNK;
  int s_arr[16], d_arr[16];
  cnt[t] = 0;
  __syncthreads();
  #pragma unroll
  for (int k = 0; k < 16; k++) {
    int idx = c0 + k * 256 + t;
    if (idx < nE) {
      s_arr[k] = esrc[idx];
      int d = edst[idx];
      d_arr[k] = d;
      atomicAdd(&cnt[d >> 9], 1);
    } else d_arr[k] = -1;
  }
  __syncthreads();
  int v = cnt[t];
  int incl = wave_incl_scan(v);
  int wid = t >> 6;
  if ((t & 63) == 63) wsum[wid] = incl;
  if (v > 0) gbase[t] = atomicAdd(&gcnt[t], v);
  __syncthreads();
  int add = 0;
  for (int w_ = 0; w_ < wid; w_++) add += wsum[w_];
  int excl = add + incl - v;
  loff[t] = excl;
  cur[t] = excl;
  if (t == 255) loff[256] = excl + v;
  __syncthreads();
  // place edges into sbuf grouped by bucket
  #pragma unroll
  for (int k = 0; k < 16; k++) {
    if (d_arr[k] >= 0) {
      int b = d_arr[k] >> 9;
      int p = atomicAdd(&cur[b], 1);
      sbuf[p] = (s_arr[k] << 9) | (d_arr[k] & 511);
    }
  }
  __syncthreads();
  // coalesced copy-out: consecutive slots -> consecutive ebuf addresses per bucket
  const int totalc = loff[256];
  for (int k = t; k < totalc; k += 256) {
    int lo = 0, hi = 255;
    while (lo < hi) {                       // largest b with loff[b] <= k
      int mid = (lo + hi + 1) >> 1;
      if (loff[mid] <= k) lo = mid; else hi = mid - 1;
    }
    ebuf[(size_t)lo * CAP + gbase[lo] + (k - loff[lo])] = sbuf[k];
  }
}

// ---------------- CSR build phase 2: per-bucket local build (LDS-sorted csr out) ----------------
__global__ __launch_bounds__(256)
void bucket_build_kernel(const int* __restrict__ ebuf, const int* __restrict__ gcnt,
                         int* __restrict__ csr, int* __restrict__ offs,
                         int* __restrict__ deg, float* __restrict__ inv_deg, int n) {
  __shared__ int hist[512];
  __shared__ int offl[512];
  __shared__ int curl[512];
  __shared__ int wsum[4];
  __shared__ int lbuf[LCAP];   // 36KB
  const int b = blockIdx.x, t = threadIdx.x;
  const int cnt = gcnt[b];
  const size_t ebase = (size_t)b * CAP;
  hist[t] = 0; hist[t + 256] = 0;
  __syncthreads();
  for (int i = t; i < cnt; i += 256) {
    int e = ebuf[ebase + i];
    atomicAdd(&hist[e & 511], 1);
  }
  __syncthreads();
  int a0 = hist[2 * t], a1 = hist[2 * t + 1];
  int s = a0 + a1;
  int incl = wave_incl_scan(s);
  int wid = t >> 6;
  if ((t & 63) == 63) wsum[wid] = incl;
  __syncthreads();
  int add = 0;
  for (int w_ = 0; w_ < wid; w_++) add += wsum[w_];
  int excl = add + incl - s;
  offl[2 * t] = excl;     offl[2 * t + 1] = excl + a0;
  curl[2 * t] = excl;     curl[2 * t + 1] = excl + a0;
  __syncthreads();
  const int d0 = b << 9;
  for (int i = t; i < 512; i += 256) {
    int g = d0 + i;
    if (g < n) {
      offs[g] = b * CAP + offl[i];
      int dg = hist[i];
      deg[g] = dg;
      inv_deg[g] = 1.0f / fmaxf((float)dg, 1.0f);
    }
  }
  __syncthreads();
  if (cnt <= LCAP) {
    for (int i = t; i < cnt; i += 256) {
      int e = ebuf[ebase + i];
      int p = atomicAdd(&curl[e & 511], 1);
      lbuf[p] = ((unsigned)e) >> 9;
    }
    __syncthreads();
    for (int i = t; i < cnt; i += 256) csr[ebase + i] = lbuf[i];   // coalesced
  } else {
    for (int i = t; i < cnt; i += 256) {
      int e = ebuf[ebase + i];
      int p = atomicAdd(&curl[e & 511], 1);
      csr[ebase + p] = ((unsigned)e) >> 9;
    }
  }
}

// ---------------- fused SAGE layer: fp8 gather (v_perm + pk_add_f16) + bf16 MFMA ----------------
template<bool EMIT_Z>
__global__ __launch_bounds__(256)
void sage_fused_kernel(const unsigned short* __restrict__ x, const unsigned char* __restrict__ xf8,
                       const int* __restrict__ csr,
                       const int* __restrict__ offs, const int* __restrict__ deg,
                       const float* __restrict__ inv_deg,
                       const unsigned short* __restrict__ Wp, const float* __restrict__ bias,
                       unsigned short* __restrict__ out, unsigned char* __restrict__ outf8,
                       const float* __restrict__ wl, const float* __restrict__ wr,
                       float* __restrict__ zl, float* __restrict__ zr, int n) {
  __shared__ int lcsr[ALCSR];
  __shared__ __align__(16) unsigned short lagg[16][136];
  __shared__ float zpart[2][4][16];
  const int t = threadIdx.x;
  const int node0 = blockIdx.x * 16;
  int last = node0 + 15; if (last >= n) last = n - 1;
  const int s_begin = offs[node0];
  const int total = offs[last] + deg[last] - s_begin;   // contiguous: 16 | NPB
  const bool useLds = (total <= ALCSR);
  if (useLds) {
    for (int k = t; k < total; k += 256) lcsr[k] = csr[s_begin + k];
  }
  __syncthreads();

  const int w = t >> 6, l = t & 63;
  {  // ---- gather phase: 4 nodes per wave, fp8 rows, packed-fp16 accumulate ----
    const int g = l >> 4, j = l & 15;
    const int node = node0 + w * 4 + g;
    if (node < n) {
      const unsigned char* xj = xf8 + 8 * j;
      const int lb = offs[node] - s_begin;
      const int d = deg[node];
      h16x2 a0[4], a1[4];
      #pragma unroll
      for (int k = 0; k < 4; k++) {
        a0[k] = (h16x2){(_Float16)0, (_Float16)0};
        a1[k] = (h16x2){(_Float16)0, (_Float16)0};
      }
      auto acc8 = [](h16x2* A, uint2 v) {
        unsigned p0 = __builtin_amdgcn_perm(0u, v.x, 0x01040004u);
        unsigned p1 = __builtin_amdgcn_perm(0u, v.x, 0x03040204u);
        unsigned p2 = __builtin_amdgcn_perm(0u, v.y, 0x01040004u);
        unsigned p3 = __builtin_amdgcn_perm(0u, v.y, 0x03040204u);
        A[0] += __builtin_bit_cast(h16x2, p0);
        A[1] += __builtin_bit_cast(h16x2, p1);
        A[2] += __builtin_bit_cast(h16x2, p2);
        A[3] += __builtin_bit_cast(h16x2, p3);
      };
      int i = 0;
      if (useLds) {
        for (; i + 3 < d; i += 4) {
          int e0 = lcsr[lb + i], e1 = lcsr[lb + i + 1];
          int e2 = lcsr[lb + i + 2], e3 = lcsr[lb + i + 3];
          uint2 v0 = *(const uint2*)(xj + (size_t)e0 * HD);
          uint2 v1 = *(const uint2*)(xj + (size_t)e1 * HD);
          uint2 v2 = *(const uint2*)(xj + (size_t)e2 * HD);
          uint2 v3 = *(const uint2*)(xj + (size_t)e3 * HD);
          acc8(a0, v0); acc8(a1, v1); acc8(a0, v2); acc8(a1, v3);
        }
        if (i + 1 < d) {
          int e0 = lcsr[lb + i], e1 = lcsr[lb + i + 1];
          uint2 v0 = *(const uint2*)(xj + (size_t)e0 * HD);
          uint2 v1 = *(const uint2*)(xj + (size_t)e1 * HD);
          acc8(a0, v0); acc8(a1, v1);
          i += 2;
        }
        if (i < d) {
          int e0 = lcsr[lb + i];
          acc8(a0, *(const uint2*)(xj + (size_t)e0 * HD));
        }
      } else {
        const int* gcsr = csr + s_begin + lb;
        for (; i + 3 < d; i += 4) {
          int e0 = gcsr[i], e1 = gcsr[i + 1], e2 = gcsr[i + 2], e3 = gcsr[i + 3];
          uint2 v0 = *(const uint2*)(xj + (size_t)e0 * HD);
          uint2 v1 = *(const uint2*)(xj + (size_t)e1 * HD);
          uint2 v2 = *(const uint2*)(xj + (size_t)e2 * HD);
          uint2 v3 = *(const uint2*)(xj + (size_t)e3 * HD);
          acc8(a0, v0); acc8(a1, v1); acc8(a0, v2); acc8(a1, v3);
        }
        if (i + 1 < d) {
          int e0 = gcsr[i], e1 = gcsr[i + 1];
          uint2 v0 = *(const uint2*)(xj + (size_t)e0 * HD);
          uint2 v1 = *(const uint2*)(xj + (size_t)e1 * HD);
          acc8(a0, v0); acc8(a1, v1);
          i += 2;
        }
        if (i < d) {
          int e0 = gcsr[i];
          acc8(a0, *(const uint2*)(xj + (size_t)e0 * HD));
        }
      }
      const float id = inv_deg[node];
      uint4 o;
      unsigned* op = (unsigned*)&o;
      #pragma unroll
      for (int k = 0; k < 4; k++) {
        float lo = ((float)a0[k][0] + (float)a1[k][0]) * id;
        float hi = ((float)a0[k][1] + (float)a1[k][1]) * id;
        op[k] = (unsigned)f2bf(lo) | ((unsigned)f2bf(hi) << 16);
      }
      *(uint4*)&lagg[w * 4 + g][j * 8] = o;
    } else {
      *(uint4*)&lagg[w * 4 + g][j * 8] = make_uint4(0, 0, 0, 0);
    }
  }
  __syncthreads();

  // ---- MFMA phase: wave w owns col-frags 2w, 2w+1 ----
  const int lr = l & 15, lg = l >> 4;
  int ra = node0 + lr; if (ra >= n) ra = n - 1;
  const unsigned short* wbase = Wp + (size_t)lr * 32 + (size_t)lg * 8;
  const unsigned short* rbase = x + (size_t)ra * HD + 8 * lg;

  f32x4 acc[2];
  #pragma unroll
  for (int c = 0; c < 2; c++) {
    float bv = bias[(2 * w + c) * 16 + lr];
    acc[c] = (f32x4){bv, bv, bv, bv};
  }
  #pragma unroll
  for (int ks = 0; ks < 4; ks++) {
    bf16x8 af = *(const bf16x8*)&lagg[lr][lg * 8 + ks * 32];
    #pragma unroll
    for (int c = 0; c < 2; c++) {
      int cb = 2 * w + c;
      bf16x8 bfv = *(const bf16x8*)(wbase + (size_t)(ks * 128 + cb * 16) * 32);
      acc[c] = __builtin_amdgcn_mfma_f32_16x16x32_bf16(af, bfv, acc[c], 0, 0, 0);
    }
  }
  #pragma unroll
  for (int ks = 0; ks < 4; ks++) {
    bf16x8 af = *(const bf16x8*)(rbase + ks * 32);
    #pragma unroll
    for (int c = 0; c < 2; c++) {
      int cb = 2 * w + c;
      bf16x8 bfv = *(const bf16x8*)(wbase + (size_t)((4 + ks) * 128 + cb * 16) * 32);
      acc[c] = __builtin_amdgcn_mfma_f32_16x16x32_bf16(af, bfv, acc[c], 0, 0, 0);
    }
  }

  if constexpr (!EMIT_Z) {
    #pragma unroll
    for (int c = 0; c < 2; c++) {
      int cb = 2 * w + c;
      #pragma unroll
      for (int r = 0; r < 4; r++) {
        int node = node0 + lg * 4 + r;
        if (node < n) {
          float val = lrelu(acc[c][r]);
          out[(size_t)node * HD + cb * 16 + lr] = f2bf(val);
          outf8[(size_t)node * HD + cb * 16 + lr] = f2e5m2(val);
        }
      }
    }
  } else {
    float vl[4] = {0.f, 0.f, 0.f, 0.f}, vr[4] = {0.f, 0.f, 0.f, 0.f};
    #pragma unroll
    for (int c = 0; c < 2; c++) {
      int cb = 2 * w + c;
      float wlv = wl[cb * 16 + lr];
      float wrv = wr[cb * 16 + lr];
      #pragma unroll
      for (int r = 0; r < 4; r++) {
        float x3 = lrelu(acc[c][r]);
        vl[r] += x3 * wlv;
        vr[r] += x3 * wrv;
      }
    }
    #pragma unroll
    for (int r = 0; r < 4; r++) {
      #pragma unroll
      for (int d = 1; d < 16; d <<= 1) {
        vl[r] += __shfl_xor(vl[r], d, 64);
        vr[r] += __shfl_xor(vr[r], d, 64);
      }
    }
    if (lr == 0) {
      #pragma unroll
      for (int r = 0; r < 4; r++) {
        zpart[0][w][lg * 4 + r] = vl[r];
        zpart[1][w][lg * 4 + r] = vr[r];
      }
    }
    __syncthreads();
    if (t < 16) {
      int node = node0 + t;
      if (node < n) {
        zl[node] = zpart[0][0][t] + zpart[0][1][t] + zpart[0][2][t] + zpart[0][3][t];
        zr[node] = zpart[1][0][t] + zpart[1][1][t] + zpart[1][2][t] + zpart[1][3][t];
      }
    }
  }
}

// ---------------- final: out = sigmoid(mean(zl) + zr + bl) ----------------
__global__ __launch_bounds__(256)
void zfinal_kernel(const float* __restrict__ zl, const float* __restrict__ zr,
                   const int* __restrict__ csr, const int* __restrict__ offs,
                   const int* __restrict__ deg, const float* __restrict__ inv_deg,
                   const float* __restrict__ bl, float* __restrict__ out, int n) {
  int i = blockIdx.x * 256 + threadIdx.x;
  if (i >= n) return;
  int s0 = offs[i], d = deg[i];
  float a = 0.f;
  #pragma unroll 4
  for (int e = 0; e < d; e++) a += zl[csr[s0 + e]];
  float s = a * inv_deg[i] + bl[0] + zr[i];
  out[i] = 1.0f / (1.0f + expf(-s));
}

extern "C" void kernel_launch(void* const* d_in, const int* in_sizes, int n_in,
                              void* d_out, int out_size, void* d_ws, size_t ws_size,
                              hipStream_t stream) {
  const float* x_gen  = (const float*)d_in[0];
  const float* x_load = (const float*)d_in[1];
  const float* x_or   = (const float*)d_in[2];
  const float* x_ex   = (const float*)d_in[3];
  const int*   edge   = (const int*)d_in[4];
  const int*   ptv    = (const int*)d_in[5];
  const float* Wg1  = (const float*)d_in[6],  *bg1  = (const float*)d_in[7];
  const float* Wg2  = (const float*)d_in[8],  *bg2  = (const float*)d_in[9];
  const float* Wld1 = (const float*)d_in[10], *bld1 = (const float*)d_in[11];
  const float* Wld2 = (const float*)d_in[12], *bld2 = (const float*)d_in[13];
  const float* Wor1 = (const float*)d_in[14], *bor1 = (const float*)d_in[15];
  const float* Wor2 = (const float*)d_in[16], *bor2 = (const float*)d_in[17];
  const float* Wex1 = (const float*)d_in[18], *bex1 = (const float*)d_in[19];
  const float* Wex2 = (const float*)d_in[20], *bex2 = (const float*)d_in[21];
  const float* Wl_h = (const float*)d_in[22], *bl_h = (const float*)d_in[23];
  const float* Wr_h = (const float*)d_in[24];
  const float* Wl_o = (const float*)d_in[25], *bl_o = (const float*)d_in[26];
  const float* Wr_o = (const float*)d_in[27];

  const int n_gen  = in_sizes[0] / 3;
  const int n_load = in_sizes[1] / 3;
  const int n_or   = in_sizes[2] / 6;
  const int n_ex   = in_sizes[3] / 6;
  const int nE     = in_sizes[4] / 2;
  const int N      = in_sizes[5];
  const int* esrc = edge;
  const int* edst = edge + nE;

  // padded segment geometry (each segment rounded to 64 rows)
  const int np0 = ((n_gen  + 63) / 64) * 64;
  const int np1 = ((n_load + 63) / 64) * 64;
  const int np2 = ((n_or   + 63) / 64) * 64;
  const int np3 = ((n_ex   + 63) / 64) * 64;
  const int NP  = np0 + np1 + np2 + np3;
  const int4 padCum    = make_int4(np0, np0 + np1, np0 + np1 + np2, NP);
  const int4 realStart = make_int4(0, n_gen, n_gen + n_load, n_gen + n_load + n_or);
  const int4 realCnt   = make_int4(n_gen, n_load, n_or, n_ex);

  const int NB = (N + NPB - 1) / NPB;   // buckets (<=256 for N<=131072)

  // ---- workspace layout ----
  size_t NPel = (size_t)NP * HD;
  size_t nel  = (size_t)N * HD;
  unsigned short* b0 = (unsigned short*)d_ws;  // h1 (padded)
  unsigned short* b1 = b0 + NPel;              // x current (bf16)
  unsigned short* b3 = b1 + nel;               // x next (bf16)
  int*  gcnt = (int*)(b3 + nel);               // 256 ints
  int*  ebuf = gcnt + 256;                     // NB*CAP packed edges
  int*  csr  = ebuf + (size_t)NB * CAP;
  int*  offs = csr + (size_t)NB * CAP;
  int*  deg  = offs + N;
  float* inv_deg = (float*)(deg + N);
  float* zl = inv_deg + N;
  float* zr = zl + N;
  int*  invp = (int*)(zr + N);
  uintptr_t wp_addr = ((uintptr_t)(invp + N) + 15) & ~(uintptr_t)15;
  unsigned short* Wp = (unsigned short*)wp_addr;   // 4*16384 + 3*32768 bf16
  uintptr_t f8_addr = ((uintptr_t)(Wp + 4 * 16384 + 3 * 32768) + 15) & ~(uintptr_t)15;
  unsigned char* f8a = (unsigned char*)f8_addr;    // N*HD bytes
  unsigned char* f8b = f8a + nel;                  // N*HD bytes

  // ---- weight repack + invptv + gcnt zero (one launch) ----
  wprep_all_kernel<<<640, 256, 0, stream>>>(Wg2, Wld2, Wor2, Wex2, Wl_h, Wr_h, Wp,
                                            ptv, invp, gcnt, N);

  // ---- embeddings (embed2 emits bf16 + fp8) ----
  embed1_kernel<<<NP / 2, 256, 0, stream>>>(x_gen, x_load, x_or, x_ex,
                                            Wg1, bg1, Wld1, bld1, Wor1, bor1, Wex1, bex1,
                                            b0, padCum, realCnt);
  mfma_embed2_kernel<<<NP / 64, 256, 0, stream>>>(b0, Wp, bg2, bld2, bor2, bex2,
                                                  invp, b1, f8a, padCum, realStart, realCnt);

  // ---- CSR build (bucketed, LDS-sorted, coalesced writes) ----
  bucket_scatter_kernel<<<(nE + SCHUNK - 1) / SCHUNK, 256, 0, stream>>>(esrc, edst, gcnt, ebuf, nE);
  bucket_build_kernel<<<NB, 256, 0, stream>>>(ebuf, gcnt, csr, offs, deg, inv_deg, N);

  // ---- hidden SAGE layers (fused fp8-gather + bf16 combine) ----
  const int fGrid = (N + 15) / 16;
  const unsigned short* WpC = Wp + 4 * 16384;
  unsigned short* xbf = b1;  unsigned char* xf8 = f8a;
  unsigned short* nbf = b3;  unsigned char* nf8 = f8b;
  for (int l = 0; l < 2; l++) {
    sage_fused_kernel<false><<<fGrid, 256, 0, stream>>>(
        xbf, xf8, csr, offs, deg, inv_deg, WpC + (size_t)l * 32768,
        bl_h + (size_t)l * HD, nbf, nf8, nullptr, nullptr, nullptr, nullptr, N);
    unsigned short* tb = xbf; xbf = nbf; nbf = tb;
    unsigned char*  tf = xf8; xf8 = nf8; nf8 = tf;
  }
  // layer 3 fused with output projection (zl = x3.Wl_o, zr = x3.Wr_o)
  sage_fused_kernel<true><<<fGrid, 256, 0, stream>>>(
      xbf, xf8, csr, offs, deg, inv_deg, WpC + 2 * 32768,
      bl_h + 2 * HD, nullptr, nullptr, Wl_o, Wr_o, zl, zr, N);

  // ---- final scalar aggregation + sigmoid ----
  zfinal_kernel<<<(N + 255) / 256, 256, 0, stream>>>(zl, zr, csr, offs, deg, inv_deg,
                                                     bl_o, (float*)d_out, N);
}